// Round 12
// baseline (1160.179 us; speedup 1.0000x reference)
//
#include <hip/hip_runtime.h>
#include <math.h>

#define NN 8192
#define REV_CAP 48
#define KNN_CAP 512   // per-wave survivor cap; P(overflow) astronomically small (order-stat bound)
#define NB 1024       // mega-kernel grid; co-residency guaranteed: __launch_bounds__(256,4) -> >=4 blk/CU, LDS 26KB <= 40KB

// ---- ws layout (float element offsets) ----
static const size_t OFF_K     = 0;        // 405
static const size_t OFF_BAR   = 408;      // 8 ints (global barrier counters, zeroed by k_setup each call)
static const size_t OFF_CNT   = 512;      // int[8192]
static const size_t OFF_REV   = 8704;     // int[8192*48]
static const size_t OFF_STATS = 401920;   // 3 layers x (768 A-partials + 768 B-partials)
static const size_t OFF_XF    = 406528;   // 8192*120 interleaved features
static const size_t OFF_YF    = 1389568;  // 8192*120 outputs (head aliased as SoA x/y/z/q for KNN)
static const size_t WS_FLOATS = 2372608;

// =================== K tensor math (device, double precision) ===================
__device__ double dfact(int n){ double r=1.0; for(int i=2;i<=n;++i) r*=(double)i; return r; }

__device__ double dcg(int j1,int m1,int j2,int m2,int j3,int m3){
  if (m1+m2!=m3) return 0.0;
  if (j3 < abs(j1-j2) || j3 > j1+j2) return 0.0;
  double pre = sqrt((double)(2*j3+1)*dfact(j3+j1-j2)*dfact(j3-j1+j2)*dfact(j1+j2-j3)/dfact(j1+j2+j3+1));
  pre *= sqrt(dfact(j3+m3)*dfact(j3-m3)*dfact(j1-m1)*dfact(j1+m1)*dfact(j2-m2)*dfact(j2+m2));
  double s=0.0;
  for(int k=0;k<=j1+j2-j3;++k){
    int d1=j1+j2-j3-k, d2=j1-m1-k, d3=j2+m2-k, d4=j3-j2+m1+k, d5=j3-j1-m2+k;
    if(d1<0||d2<0||d3<0||d4<0||d5<0) continue;
    double den = dfact(k)*dfact(d1)*dfact(d2)*dfact(d3)*dfact(d4)*dfact(d5);
    s += ((k&1)? -1.0: 1.0)/den;
  }
  return pre*s;
}

__device__ int qrow(int l,int r,int* col,double* re,double* im){
  const double s = 0.70710678118654752440;
  if (r==l){ col[0]=l; re[0]=1.0; im[0]=0.0; return 1; }
  if (r>l){ int m=r-l;
    col[0]=l+m; re[0]=((m&1)?-s:s); im[0]=0.0;
    col[1]=l-m; re[1]=s;            im[1]=0.0;
  } else { int m=l-r;
    col[0]=l+m; re[0]=0.0; im[0]=((m&1)? s : -s);
    col[1]=l-m; re[1]=0.0; im[1]=s;
  }
  return 2;
}

// =================== fused setup: xf init | SoA+q | cnt | bars | K ===================
__global__ __launch_bounds__(256) void k_setup(const float* __restrict__ pos,
        const float* __restrict__ W_emb, float* __restrict__ Kbuf,
        float* __restrict__ xf,
        float* __restrict__ xs, float* __restrict__ ys, float* __restrict__ zs,
        float* __restrict__ qs,
        int* __restrict__ cnt, int* __restrict__ bar){
  int idx = blockIdx.x*256 + threadIdx.x;
  if (idx < 983040) { const int c = idx%120; xf[idx] = (c<32)? W_emb[c] : 0.f; return; }
  idx -= 983040;
  if (idx < 8192) {
    const float x=pos[3*idx], y=pos[3*idx+1], z=pos[3*idx+2];
    xs[idx]=x; ys[idx]=y; zs[idx]=z; qs[idx]=0.5f*(x*x+y*y+z*z);
    return;
  }
  idx -= 8192;
  if (idx < 8192) { cnt[idx]=0; return; }
  idx -= 8192;
  if (idx < 8) { bar[idx]=0; return; }
  idx -= 8;
  if (idx >= 405) return;

  const int tid = idx;
  const int sizes[9]={1,25,9,45,75,25,25,75,125};
  const int l1s[9]={0,0,1,1,1,2,2,2,2};
  const int l2s[9]={0,2,0,2,2,0,2,2,2};
  const int l3s[9]={0,2,1,1,2,2,0,1,2};
  int p=0, rem=tid;
  for(p=0;p<9;++p){ if(rem < sizes[p]) break; rem -= sizes[p]; }
  const int l1=l1s[p], l2=l2s[p], l3=l3s[p];
  const int n1=2*l1+1, n2=2*l2+1;
  const int c = rem/(n1*n2); const int r2 = rem%(n1*n2); const int a=r2/n2; const int b=r2%n2;

  int c3[2],c1[2],c2[2]; double re3[2],im3[2],re1[2],im1[2],re2[2],im2[2];
  const int nc3 = qrow(l3,c,c3,re3,im3);
  const int nc1 = qrow(l1,a,c1,re1,im1);
  const int nc2 = qrow(l2,b,c2,re2,im2);

  double accRe=0, accIm=0;
  for(int i3=0;i3<nc3;++i3){
    const double q3re=re3[i3], q3im=-im3[i3];
    for(int i1=0;i1<nc1;++i1){
      const double pre_re = q3re*re1[i1] - q3im*im1[i1];
      const double pre_im = q3re*im1[i1] + q3im*re1[i1];
      for(int i2=0;i2<nc2;++i2){
        const double cgv = dcg(l1, c1[i1]-l1, l2, c2[i2]-l2, l3, c3[i3]-l3);
        if (cgv==0.0) continue;
        accRe += (pre_re*re2[i2] - pre_im*im2[i2])*cgv;
        accIm += (pre_re*im2[i2] + pre_im*re2[i2])*cgv;
      }
    }
  }
  const bool useImag = ((l1+l2+l3)&1)!=0;
  Kbuf[tid] = (float)(useImag? accIm : accRe);
}

// =================== exact 9-NN (round-9 k_knn4 verbatim) ===================
__global__ __launch_bounds__(256) void k_knn4(const float* __restrict__ xs,
                                              const float* __restrict__ ys,
                                              const float* __restrict__ zs,
                                              const float* __restrict__ qs,
                                              int* __restrict__ cnt, int* __restrict__ rev){
  const int lane = threadIdx.x & 63;
  const int w    = threadIdx.x >> 6;
  const int node = blockIdx.x*4 + w;
  __shared__ float sdist[4][KNN_CAP];
  __shared__ int   sidx[4][KNN_CAP];
  __shared__ int   scount[4];
  if (threadIdx.x < 4) scount[threadIdx.x]=0;
  __syncthreads();

  const float px = xs[node], py = ys[node], pz = zs[node];

  float m1 = INFINITY, m2 = INFINITY;
  for(int c=0;c<4;++c){
    const int base = (c*64 + lane)*4;
    const float4 fx = *(const float4*)(xs + base);
    const float4 fy = *(const float4*)(ys + base);
    const float4 fz = *(const float4*)(zs + base);
    const float4 fq = *(const float4*)(qs + base);
    float ss[4];
    ss[0] = fmaf(-px,fx.x, fmaf(-py,fy.x, fmaf(-pz,fz.x, fq.x)));
    ss[1] = fmaf(-px,fx.y, fmaf(-py,fy.y, fmaf(-pz,fz.y, fq.y)));
    ss[2] = fmaf(-px,fx.z, fmaf(-py,fy.z, fmaf(-pz,fz.z, fq.z)));
    ss[3] = fmaf(-px,fx.w, fmaf(-py,fy.w, fmaf(-pz,fz.w, fq.w)));
    #pragma unroll
    for(int q=0;q<4;++q){
      const float hi = fmaxf(m1, ss[q]);
      m1 = fminf(m1, ss[q]);
      m2 = fminf(m2, hi);
    }
  }
  float T = INFINITY;
  for(int r=0;r<9;++r){
    float v = m1; int l = lane;
    #pragma unroll
    for(int s=32;s>0;s>>=1){
      const float ov=__shfl_xor(v,s,64); const int ol=__shfl_xor(l,s,64);
      if (ov<v || (ov==v && ol<l)){ v=ov; l=ol; }
    }
    T = v;
    if (lane==l){ m1=m2; m2=INFINITY; }
  }

  for(int c=0;c<32;++c){
    const int base = (c*64 + lane)*4;
    const float4 fx = *(const float4*)(xs + base);
    const float4 fy = *(const float4*)(ys + base);
    const float4 fz = *(const float4*)(zs + base);
    const float4 fq = *(const float4*)(qs + base);
    float ss[4];
    ss[0] = fmaf(-px,fx.x, fmaf(-py,fy.x, fmaf(-pz,fz.x, fq.x)));
    ss[1] = fmaf(-px,fx.y, fmaf(-py,fy.y, fmaf(-pz,fz.y, fq.y)));
    ss[2] = fmaf(-px,fx.z, fmaf(-py,fy.z, fmaf(-pz,fz.z, fq.z)));
    ss[3] = fmaf(-px,fx.w, fmaf(-py,fy.w, fmaf(-pz,fz.w, fq.w)));
    #pragma unroll
    for(int q=0;q<4;++q){
      if (ss[q] <= T){
        int pos = atomicAdd(&scount[w],1);
        if (pos < KNN_CAP){ sdist[w][pos]=ss[q]; sidx[w][pos]=base+q; }
      }
    }
  }
  __syncthreads();

  int m = scount[w]; if (m > KNN_CAP) m = KNN_CAP;
  float dl[KNN_CAP/64]; int il[KNN_CAP/64];
  #pragma unroll
  for(int k=0;k<KNN_CAP/64;++k){
    const int j = lane + 64*k;
    if (j < m){ dl[k]=sdist[w][j]; il[k]=sidx[w][j]; }
    else      { dl[k]=INFINITY;    il[k]=0x7fffffff; }
  }
  for(int r=0;r<9;++r){
    float bv=dl[0]; int bi=il[0];
    #pragma unroll
    for(int k=1;k<KNN_CAP/64;++k){
      if (dl[k]<bv || (dl[k]==bv && il[k]<bi)){ bv=dl[k]; bi=il[k]; }
    }
    float v=bv; int ix=bi;
    #pragma unroll
    for(int s=32;s>0;s>>=1){
      float ov=__shfl_xor(v,s,64); int oi=__shfl_xor(ix,s,64);
      if (ov<v || (ov==v && oi<ix)){ v=ov; ix=oi; }
    }
    if (ix != node && lane==0){
      int cpos = atomicAdd(&cnt[ix],1);
      if (cpos < REV_CAP) rev[ix*REV_CAP + cpos] = node;
    }
    #pragma unroll
    for(int k=0;k<KNN_CAP/64;++k){
      if (il[k]==ix){ dl[k]=INFINITY; il[k]=0x7fffffff; }
    }
  }
}

// ---- device-scope grid barrier: single-use counters, all NB blocks co-resident ----
__device__ __forceinline__ void gbar(int* bar, int id){
  __syncthreads();
  if (threadIdx.x==0){
    __threadfence();                       // release: drain writes past per-XCD L2
    atomicAdd(&bar[id], 1);                // RMW at coherence point
    while (atomicAdd(&bar[id], 0) < NB) __builtin_amdgcn_s_sleep(8);
    __threadfence();                       // acquire: invalidate stale cache
  }
  __syncthreads();
}

// =================== persistent mega-kernel: 3 x (msg -> stats -> norm) + normmlp ===================
// Grid = NB=1024 blocks x 256 (4 waves). Each block: 2 rounds x 4 nodes for msg.
// All stage bodies are byte-level ports of the round-9/10 passing kernels.
__global__ __launch_bounds__(256, 4) void k_layers(
  const float* __restrict__ pos,
  const int* __restrict__ cnt, const int* __restrict__ rev,
  const float* __restrict__ Kbuf,
  float* __restrict__ xf, float* __restrict__ yf,
  const float* __restrict__ tpw_b,
  const float* __restrict__ W0b, const float* __restrict__ W1b, const float* __restrict__ W2b,
  const float* __restrict__ bw0b,const float* __restrict__ bb0b,
  const float* __restrict__ bw1b,const float* __restrict__ bw2b,
  const float* __restrict__ Wf1, const float* __restrict__ Wf2,
  const float* __restrict__ bf2, const float* __restrict__ Wf3,
  const float* __restrict__ bf3,
  float* __restrict__ stats, float* __restrict__ out, int* __restrict__ bar)
{
  __shared__ float S[6501];
  float* KL   = S;            // 405
  float* TW   = S+405;        // 144
  float* momP = S+549;        // 4*120
  float* momS = S+1029;       // 4*600
  float* aSb  = S+3429;       // 4*480
  int*   eIdx = (int*)(S+5349); // 4*48
  float* eSh  = S+5541;       // 4*5*48 -> ends 6501

  const int t = threadIdx.x;
  const int w = t >> 6;
  const int lane = t & 63;
  const float s15 = 3.8729833462f, s5c = 2.2360679775f;
  int barid = 0;

  for(int l=0;l<3;++l){
    float* pA = stats + l*1536;
    float* pB = pA + 768;
    const float* tpw = tpw_b + l*144;
    const float* W0 = W0b + l*40*32;
    const float* W1 = W1b + l*40*16;
    const float* W2 = W2b + l*64*8;

    __syncthreads();   // S reuse guard (prev stage)
    for(int q=t;q<405;q+=256) KL[q]=Kbuf[q];
    for(int q=t;q<144;q+=256) TW[q]=tpw[q];
    __syncthreads();

    // ---- msg: 2 rounds x 4 nodes/block ----
    for(int r=0;r<2;++r){
      const int n = blockIdx.x*8 + r*4 + w;

      // Stage 1a: parallel edge geometry
      const int deg0 = cnt[n];
      const int deg = (deg0<REV_CAP)? deg0 : REV_CAP;
      const float pnx=pos[3*n], pny=pos[3*n+1], pnz=pos[3*n+2];
      if (lane < deg){
        const int i = rev[n*REV_CAP+lane];
        eIdx[w*REV_CAP+lane] = i;
        const float ex = pnx - pos[3*i], ey = pny - pos[3*i+1], ez = pnz - pos[3*i+2];
        const float rn = sqrtf(ex*ex+ey*ey+ez*ez) + 1e-12f;
        const float ux=ex/rn, uy=ey/rn, uz=ez/rn;
        eSh[(w*5+0)*REV_CAP+lane]=s15*ux*uy;
        eSh[(w*5+1)*REV_CAP+lane]=s15*uy*uz;
        eSh[(w*5+2)*REV_CAP+lane]=0.5f*s5c*(3.f*uz*uz-1.f);
        eSh[(w*5+3)*REV_CAP+lane]=s15*ux*uz;
        eSh[(w*5+4)*REV_CAP+lane]=0.5f*s15*(ux*ux-uy*uy);
      }
      __syncthreads();

      // Stage 1b: moment accumulation
      const int c0 = lane*2;
      float mp0=0.f, mp1=0.f;
      float ms0[5], ms1[5];
      #pragma unroll
      for(int j=0;j<5;++j){ ms0[j]=0.f; ms1[j]=0.f; }
      for(int e=0;e<deg;++e){
        const int i = eIdx[w*REV_CAP+e];
        const float sh0=eSh[(w*5+0)*REV_CAP+e], sh1=eSh[(w*5+1)*REV_CAP+e], sh2=eSh[(w*5+2)*REV_CAP+e];
        const float sh3=eSh[(w*5+3)*REV_CAP+e], sh4=eSh[(w*5+4)*REV_CAP+e];
        if (lane<60){
          const float2 f = *(const float2*)(xf + (size_t)i*120 + c0);
          mp0 += f.x; mp1 += f.y;
          ms0[0]+=f.x*sh0; ms0[1]+=f.x*sh1; ms0[2]+=f.x*sh2; ms0[3]+=f.x*sh3; ms0[4]+=f.x*sh4;
          ms1[0]+=f.y*sh0; ms1[1]+=f.y*sh1; ms1[2]+=f.y*sh2; ms1[3]+=f.y*sh3; ms1[4]+=f.y*sh4;
        }
      }
      if (lane<60){
        momP[w*120+c0]=mp0; momP[w*120+c0+1]=mp1;
        #pragma unroll
        for(int j=0;j<5;++j){ momS[w*600+c0*5+j]=ms0[j]; momS[w*600+(c0+1)*5+j]=ms1[j]; }
      }
      __syncthreads();

      // Stage 2: per-node K-contraction
      float acc[14];
      #pragma unroll
      for(int k=0;k<14;++k) acc[k]=0.f;

      if (lane<32){
        const int u=lane;
        const float rw0=TW[u], rw1=TW[32+u];
        acc[0] = rw0 * KL[0] * momP[w*120+u];                    // p1
        float m0s[5];
        #pragma unroll
        for(int j=0;j<5;++j) m0s[j]=momS[w*600+u*5+j];
        #pragma unroll
        for(int o=0;o<5;++o){ float g=0.f;                       // p2
          #pragma unroll
          for(int j=0;j<5;++j) g += KL[1+o*5+j]*m0s[j];
          acc[1+o] = rw1*g; }
      } else if (lane<48){
        const int u=lane-32;
        const float rw0=TW[64+u], rw1=TW[80+u], rw2=TW[96+u];
        float m1p[3], m1s[3][5];
        #pragma unroll
        for(int i=0;i<3;++i){
          m1p[i]=momP[w*120+32+u*3+i];
          #pragma unroll
          for(int j=0;j<5;++j) m1s[i][j]=momS[w*600+(32+u*3+i)*5+j];
        }
        #pragma unroll
        for(int o=0;o<3;++o){ float g=0.f;                       // p3
          #pragma unroll
          for(int i=0;i<3;++i) g += KL[26+o*3+i]*m1p[i];
          acc[o]=rw0*g; }
        #pragma unroll
        for(int o=0;o<3;++o){ float g=0.f;                       // p4
          #pragma unroll
          for(int i=0;i<3;++i)
            #pragma unroll
            for(int j=0;j<5;++j) g += KL[35+(o*3+i)*5+j]*m1s[i][j];
          acc[3+o]=rw1*g; }
        #pragma unroll
        for(int o=0;o<5;++o){ float g=0.f;                       // p5
          #pragma unroll
          for(int i=0;i<3;++i)
            #pragma unroll
            for(int j=0;j<5;++j) g += KL[80+(o*3+i)*5+j]*m1s[i][j];
          acc[6+o]=rw2*g; }
      } else if (lane<56){
        const int u=lane-48;
        const float rw0=TW[112+u], rw1=TW[120+u], rw2=TW[128+u], rw3=TW[136+u];
        float m2p[5], m2s[5][5];
        #pragma unroll
        for(int i=0;i<5;++i){
          m2p[i]=momP[w*120+80+u*5+i];
          #pragma unroll
          for(int j=0;j<5;++j) m2s[i][j]=momS[w*600+(80+u*5+i)*5+j];
        }
        #pragma unroll
        for(int o=0;o<5;++o){ float g=0.f;                       // p6
          #pragma unroll
          for(int i=0;i<5;++i) g += KL[155+o*5+i]*m2p[i];
          acc[o]=rw0*g; }
        { float g=0.f;                                           // p7
          #pragma unroll
          for(int i=0;i<5;++i)
            #pragma unroll
            for(int j=0;j<5;++j) g += KL[180+i*5+j]*m2s[i][j];
          acc[5]=rw1*g; }
        #pragma unroll
        for(int o=0;o<3;++o){ float g=0.f;                       // p8
          #pragma unroll
          for(int i=0;i<5;++i)
            #pragma unroll
            for(int j=0;j<5;++j) g += KL[205+(o*5+i)*5+j]*m2s[i][j];
          acc[6+o]=rw2*g; }
        #pragma unroll
        for(int o=0;o<5;++o){ float g=0.f;                       // p9
          #pragma unroll
          for(int i=0;i<5;++i)
            #pragma unroll
            for(int j=0;j<5;++j) g += KL[280+(o*5+i)*5+j]*m2s[i][j];
          acc[9+o]=rw3*g; }
      }

      // scatter into aS
      float* aS = aSb + w*480;
      if (lane<32){
        aS[lane] = acc[0];
        #pragma unroll
        for(int o=0;o<5;++o) aS[160 + lane*5+o] = acc[1+o];
      } else if (lane<48){
        const int uu=lane-32;
        #pragma unroll
        for(int m=0;m<3;++m){ aS[40 + uu*3+m] = acc[m]; aS[40 + (16+uu)*3+m] = acc[3+m]; }
        #pragma unroll
        for(int o=0;o<5;++o) aS[160 + (32+uu)*5+o] = acc[6+o];
      } else if (lane<56){
        const int uu=lane-48;
        aS[32+uu] = acc[5];
        #pragma unroll
        for(int m=0;m<3;++m) aS[40 + (32+uu)*3+m] = acc[6+m];
        #pragma unroll
        for(int o=0;o<5;++o){ aS[160 + (48+uu)*5+o] = acc[o]; aS[160 + (56+uu)*5+o] = acc[9+o]; }
      }
      __syncthreads();

      // Stage 3: linear mixes -> yf
      const float inv40 = 0.15811388300841896660f;
      for(int q=lane;q<120;q+=64){
        float o_;
        if (q<32){
          float g=0.f;
          for(int uu=0;uu<40;++uu) g += aS[uu]*W0[uu*32+q];
          o_ = g*inv40;
        } else if (q<80){
          const int e=q-32, v=e/3, m=e%3;
          float g=0.f;
          for(int uu=0;uu<40;++uu) g += aS[40+uu*3+m]*W1[uu*16+v];
          o_ = g*inv40;
        } else {
          const int e=q-80, tt=e/5, m=e%5;
          float g=0.f;
          for(int uu=0;uu<64;++uu) g += aS[160+uu*5+m]*W2[uu*8+tt];
          o_ = g*0.125f;
        }
        yf[(size_t)n*120+q] = o_;
      }
      __syncthreads();
    }
    gbar(bar, barid++);   // msg -> statp

    // ---- statp: blocks 0..767 (r9-verbatim math; S reused as r1/r2) ----
    {
      float* r1 = S; float* r2 = S+256;
      if (blockIdx.x < 768){
        const int ch = blockIdx.x % 96;
        const int chunk = blockIdx.x / 96;
        const int n0 = chunk*1024;
        float a1=0.f, a2=0.f;
        if (ch<32){
          for(int nn=t;nn<1024;nn+=256){ float v=yf[(size_t)(n0+nn)*120+ch]; a1+=v; a2+=v*v; }
        } else if (ch<48){
          const int v_=ch-32;
          for(int nn=t;nn<1024;nn+=256){
            #pragma unroll
            for(int m=0;m<3;++m){ float v=yf[(size_t)(n0+nn)*120+32+v_*3+m]; a2+=v*v; }
          }
        } else {
          const int t_=ch-48;
          for(int nn=t;nn<1024;nn+=256){
            #pragma unroll
            for(int m=0;m<5;++m){ float v=yf[(size_t)(n0+nn)*120+80+t_*5+m]; a2+=v*v; }
          }
        }
        r1[t]=a1; r2[t]=a2; __syncthreads();
        for(int s=128;s>0;s>>=1){ if(t<s){ r1[t]+=r1[t+s]; r2[t]+=r2[t+s]; } __syncthreads(); }
        if(t==0){ pA[ch*8+chunk]=r1[0]; pB[ch*8+chunk]=r2[0]; }
      }
    }
    gbar(bar, barid++);   // statp -> norm / normmlp

    // ---- norm (layers 0,1): per-block finalize + apply ----
    if (l<2){
      const float* bw0 = bw0b + l*32; const float* bb0 = bb0b + l*32;
      const float* bw1 = bw1b + l*16; const float* bw2 = bw2b + l*8;
      float* sc = S; float* sf = S+96;
      __syncthreads();
      if (t<96){
        float sB=0.f;
        #pragma unroll
        for(int k=0;k<8;++k) sB += pB[t*8+k];
        float scale;
        if (t<32){
          float sA=0.f;
          #pragma unroll
          for(int k=0;k<8;++k) sA += pA[t*8+k];
          const float mean = sA*(1.f/8192.f);
          const float var  = sB*(1.f/8192.f) - mean*mean;
          const float inv  = 1.f/sqrtf(var+1e-5f);
          scale = bw0[t]*inv;
          sf[t] = bb0[t] - mean*scale;
        } else if (t<48){
          scale = bw1[t-32]/sqrtf(sB*(1.f/(8192.f*3.f))+1e-5f);
        } else {
          scale = bw2[t-48]/sqrtf(sB*(1.f/(8192.f*5.f))+1e-5f);
        }
        sc[t]=scale;
      }
      __syncthreads();
      // 960 elements per block
      for(int k=0;k<4;++k){
        const int idx = blockIdx.x*960 + k*256 + t;
        if (idx < (blockIdx.x+1)*960 && idx < NN*120){
          const int c = idx%120;
          const int chan = (c<32)? c : ((c<80)? 32+(c-32)/3 : 48+(c-80)/5);
          const float v = yf[idx]*sc[chan] + ((c<32)? sf[c] : 0.f);
          xf[idx] += fmaxf(v,0.f);
        }
      }
      gbar(bar, barid++);   // norm -> next msg
    }
  }

  // ---- fused layer-3 norm (x0 only) + final MLP ----
  {
    const float* pA = stats + 2*1536;
    const float* pB = pA + 768;
    const float* bw0 = bw0b + 64; const float* bb0 = bb0b + 64;
    float* w1 = S;        // 1024
    float* w2 = S+1024;   // 512
    float* w3 = S+1536;   // 32
    float* b2 = S+1568;   // 16
    float* b3 = S+1584;   // 2
    float* sc0 = S+1586;  // 32
    float* sf0 = S+1618;  // 32
    __syncthreads();
    for(int q=t;q<1024;q+=256) w1[q]=Wf1[q];
    for(int q=t;q<512;q+=256)  w2[q]=Wf2[q];
    if(t<32) w3[t]=Wf3[t];
    if(t<16) b2[t]=bf2[t];
    if(t<2)  b3[t]=bf3[t];
    if(t<32){
      float sA=0.f, sB=0.f;
      #pragma unroll
      for(int k=0;k<8;++k){ sA += pA[t*8+k]; sB += pB[t*8+k]; }
      const float mean = sA*(1.f/8192.f);
      const float var  = sB*(1.f/8192.f) - mean*mean;
      const float inv  = 1.f/sqrtf(var+1e-5f);
      sc0[t] = bw0[t]*inv;
      sf0[t] = bb0[t] - mean*sc0[t];
    }
    __syncthreads();
    if (t < 8){
      const int n = blockIdx.x*8 + t;
      float xv[32];
      #pragma unroll
      for(int k=0;k<32;++k){
        const float v = yf[(size_t)n*120+k]*sc0[k] + sf0[k];
        xv[k] = xf[(size_t)n*120+k] + fmaxf(v,0.f);
      }
      const float inv32 = 0.17677669529663688110f;
      float h1[32];
      #pragma unroll 4
      for(int c=0;c<32;++c){ float g=0.f;
        #pragma unroll
        for(int k=0;k<32;++k) g+=xv[k]*w1[k*32+c];
        h1[c]=fmaxf(g*inv32,0.f); }
      float h2[16];
      #pragma unroll 4
      for(int c=0;c<16;++c){ float g=b2[c];
        #pragma unroll
        for(int k=0;k<32;++k) g+=h1[k]*w2[k*16+c];
        h2[c]=fmaxf(g,0.f); }
      #pragma unroll
      for(int m=0;m<2;++m){ float g=b3[m];
        #pragma unroll
        for(int k=0;k<16;++k) g+=h2[k]*w3[k*2+m];
        out[n*2+m]=g; }
    }
  }
}

extern "C" void kernel_launch(void* const* d_in, const int* in_sizes, int n_in,
                              void* d_out, int out_size, void* d_ws, size_t ws_size,
                              hipStream_t stream) {
  const float* positions = (const float*)d_in[0];
  const float* W_emb  = (const float*)d_in[1];
  const float* tp_w   = (const float*)d_in[2];
  const float* lin_W0 = (const float*)d_in[3];
  const float* lin_W1 = (const float*)d_in[4];
  const float* lin_W2 = (const float*)d_in[5];
  const float* bn_w0  = (const float*)d_in[6];
  const float* bn_b0  = (const float*)d_in[7];
  const float* bn_w1  = (const float*)d_in[8];
  const float* bn_w2  = (const float*)d_in[9];
  const float* Wf1 = (const float*)d_in[10];
  const float* Wf2 = (const float*)d_in[11];
  const float* bf2 = (const float*)d_in[12];
  const float* Wf3 = (const float*)d_in[13];
  const float* bf3 = (const float*)d_in[14];

  if (ws_size < WS_FLOATS*sizeof(float)) return;

  float* ws    = (float*)d_ws;
  float* Kbuf  = ws + OFF_K;
  int*   bar   = (int*)(ws + OFF_BAR);
  int*   cnt   = (int*)(ws + OFF_CNT);
  int*   rev   = (int*)(ws + OFF_REV);
  float* stats = ws + OFF_STATS;   // 3 layers x (768 pA | 768 pB)
  float* xf = ws + OFF_XF;
  float* yf = ws + OFF_YF;

  // SoA position arrays alias the head of yf (dead after k_knn4; first msg rewrites yf)
  float* xs = yf;
  float* ysA = yf + NN;
  float* zs = yf + 2*NN;
  float* qs = yf + 3*NN;

  k_setup<<<3906,256,0,stream>>>(positions, W_emb, Kbuf, xf, xs, ysA, zs, qs, cnt, bar);
  k_knn4<<<NN/4,256,0,stream>>>(xs, ysA, zs, qs, cnt, rev);
  k_layers<<<NB,256,0,stream>>>(positions, cnt, rev, Kbuf, xf, yf,
                                tp_w, lin_W0, lin_W1, lin_W2,
                                bn_w0, bn_b0, bn_w1, bn_w2,
                                Wf1, Wf2, bf2, Wf3, bf3,
                                stats, (float*)d_out, bar);
}

// Round 13
// 320.519 us; speedup vs baseline: 3.6197x; 3.6197x over previous
//
#include <hip/hip_runtime.h>
#include <math.h>

#define NN 8192
#define REV_CAP 48
#define KNN_CAP 448   // per-wave survivor cap (expected ~72; P(overflow) astronomically small)
#define TILE 1024

// ---- ws layout (float element offsets) ----
static const size_t OFF_K     = 0;        // 405
static const size_t OFF_CNT   = 512;      // int[8192]
static const size_t OFF_REV   = 8704;     // int[8192*48]
static const size_t OFF_STATS = 401920;   // 3 layers x (768 A-partials + 768 B-partials)
static const size_t OFF_XF    = 406528;   // 8192*120 interleaved features
static const size_t OFF_YF    = 1389568;  // 8192*120 outputs (head aliased as SoA x/y/z/q for KNN)
static const size_t WS_FLOATS = 2372608;

// =================== K tensor math (device, double precision) ===================
__device__ double dfact(int n){ double r=1.0; for(int i=2;i<=n;++i) r*=(double)i; return r; }

__device__ double dcg(int j1,int m1,int j2,int m2,int j3,int m3){
  if (m1+m2!=m3) return 0.0;
  if (j3 < abs(j1-j2) || j3 > j1+j2) return 0.0;
  double pre = sqrt((double)(2*j3+1)*dfact(j3+j1-j2)*dfact(j3-j1+j2)*dfact(j1+j2-j3)/dfact(j1+j2+j3+1));
  pre *= sqrt(dfact(j3+m3)*dfact(j3-m3)*dfact(j1-m1)*dfact(j1+m1)*dfact(j2-m2)*dfact(j2+m2));
  double s=0.0;
  for(int k=0;k<=j1+j2-j3;++k){
    int d1=j1+j2-j3-k, d2=j1-m1-k, d3=j2+m2-k, d4=j3-j2+m1+k, d5=j3-j1-m2+k;
    if(d1<0||d2<0||d3<0||d4<0||d5<0) continue;
    double den = dfact(k)*dfact(d1)*dfact(d2)*dfact(d3)*dfact(d4)*dfact(d5);
    s += ((k&1)? -1.0: 1.0)/den;
  }
  return pre*s;
}

__device__ int qrow(int l,int r,int* col,double* re,double* im){
  const double s = 0.70710678118654752440;
  if (r==l){ col[0]=l; re[0]=1.0; im[0]=0.0; return 1; }
  if (r>l){ int m=r-l;
    col[0]=l+m; re[0]=((m&1)?-s:s); im[0]=0.0;
    col[1]=l-m; re[1]=s;            im[1]=0.0;
  } else { int m=l-r;
    col[0]=l+m; re[0]=0.0; im[0]=((m&1)? s : -s);
    col[1]=l-m; re[1]=0.0; im[1]=s;
  }
  return 2;
}

// =================== fused setup: xf init | SoA+q | cnt | K ===================
__global__ __launch_bounds__(256) void k_setup(const float* __restrict__ pos,
        const float* __restrict__ W_emb, float* __restrict__ Kbuf,
        float* __restrict__ xf,
        float* __restrict__ xs, float* __restrict__ ys, float* __restrict__ zs,
        float* __restrict__ qs,
        int* __restrict__ cnt){
  int idx = blockIdx.x*256 + threadIdx.x;
  if (idx < 983040) { const int c = idx%120; xf[idx] = (c<32)? W_emb[c] : 0.f; return; }
  idx -= 983040;
  if (idx < 8192) {
    const float x=pos[3*idx], y=pos[3*idx+1], z=pos[3*idx+2];
    xs[idx]=x; ys[idx]=y; zs[idx]=z; qs[idx]=0.5f*(x*x+y*y+z*z);
    return;
  }
  idx -= 8192;
  if (idx < 8192) { cnt[idx]=0; return; }
  idx -= 8192;
  if (idx >= 405) return;

  const int tid = idx;
  const int sizes[9]={1,25,9,45,75,25,25,75,125};
  const int l1s[9]={0,0,1,1,1,2,2,2,2};
  const int l2s[9]={0,2,0,2,2,0,2,2,2};
  const int l3s[9]={0,2,1,1,2,2,0,1,2};
  int p=0, rem=tid;
  for(p=0;p<9;++p){ if(rem < sizes[p]) break; rem -= sizes[p]; }
  const int l1=l1s[p], l2=l2s[p], l3=l3s[p];
  const int n1=2*l1+1, n2=2*l2+1;
  const int c = rem/(n1*n2); const int r2 = rem%(n1*n2); const int a=r2/n2; const int b=r2%n2;

  int c3[2],c1[2],c2[2]; double re3[2],im3[2],re1[2],im1[2],re2[2],im2[2];
  const int nc3 = qrow(l3,c,c3,re3,im3);
  const int nc1 = qrow(l1,a,c1,re1,im1);
  const int nc2 = qrow(l2,b,c2,re2,im2);

  double accRe=0, accIm=0;
  for(int i3=0;i3<nc3;++i3){
    const double q3re=re3[i3], q3im=-im3[i3];
    for(int i1=0;i1<nc1;++i1){
      const double pre_re = q3re*re1[i1] - q3im*im1[i1];
      const double pre_im = q3re*im1[i1] + q3im*re1[i1];
      for(int i2=0;i2<nc2;++i2){
        const double cgv = dcg(l1, c1[i1]-l1, l2, c2[i2]-l2, l3, c3[i3]-l3);
        if (cgv==0.0) continue;
        accRe += (pre_re*re2[i2] - pre_im*im2[i2])*cgv;
        accIm += (pre_re*im2[i2] + pre_im*re2[i2])*cgv;
      }
    }
  }
  const bool useImag = ((l1+l2+l3)&1)!=0;
  Kbuf[tid] = (float)(useImag? accIm : accRe);
}

// =================== exact 9-NN: knn4 skeleton + block-level LDS tile staging ===================
// Each block stages 1024-candidate tiles (x/y/z/q) into LDS once; each wave scans its OWN
// query from LDS (same FMA count and survivor logic as the proven knn4; 4x less L2 traffic).
__global__ __launch_bounds__(256) void k_knn6(const float* __restrict__ xs,
                                              const float* __restrict__ ys,
                                              const float* __restrict__ zs,
                                              const float* __restrict__ qs,
                                              int* __restrict__ cnt, int* __restrict__ rev){
  const int lane = threadIdx.x & 63;
  const int w    = threadIdx.x >> 6;
  const int node = blockIdx.x*4 + w;
  __shared__ float sdist[4][KNN_CAP];
  __shared__ int   sidx[4][KNN_CAP];
  __shared__ int   scount[4];
  __shared__ float tx[TILE], ty[TILE], tz[TILE], tq[TILE];
  if (threadIdx.x < 4) scount[threadIdx.x]=0;

  const float px = xs[node], py = ys[node], pz = zs[node];

  // stage tile 0 (candidates 0..1023)
  {
    const int i = threadIdx.x;
    ((float4*)tx)[i] = ((const float4*)xs)[i];
    ((float4*)ty)[i] = ((const float4*)ys)[i];
    ((float4*)tz)[i] = ((const float4*)zs)[i];
    ((float4*)tq)[i] = ((const float4*)qs)[i];
  }
  __syncthreads();

  // Phase 1 (knn4-identical math, reads from LDS tile 0): per-lane top-2 -> bound T
  float m1 = INFINITY, m2 = INFINITY;
  for(int c=0;c<4;++c){
    const int fi = c*64 + lane;
    const float4 fx = ((const float4*)tx)[fi];
    const float4 fy = ((const float4*)ty)[fi];
    const float4 fz = ((const float4*)tz)[fi];
    const float4 fq = ((const float4*)tq)[fi];
    float ss[4];
    ss[0] = fmaf(-px,fx.x, fmaf(-py,fy.x, fmaf(-pz,fz.x, fq.x)));
    ss[1] = fmaf(-px,fx.y, fmaf(-py,fy.y, fmaf(-pz,fz.y, fq.y)));
    ss[2] = fmaf(-px,fx.z, fmaf(-py,fy.z, fmaf(-pz,fz.z, fq.z)));
    ss[3] = fmaf(-px,fx.w, fmaf(-py,fy.w, fmaf(-pz,fz.w, fq.w)));
    #pragma unroll
    for(int q=0;q<4;++q){
      const float hi = fmaxf(m1, ss[q]);
      m1 = fminf(m1, ss[q]);
      m2 = fminf(m2, hi);
    }
  }
  float T = INFINITY;
  for(int r=0;r<9;++r){
    float v = m1; int l = lane;
    #pragma unroll
    for(int s=32;s>0;s>>=1){
      const float ov=__shfl_xor(v,s,64); const int ol=__shfl_xor(l,s,64);
      if (ov<v || (ov==v && ol<l)){ v=ov; l=ol; }
    }
    T = v;
    if (lane==l){ m1=m2; m2=INFINITY; }
  }

  // Phase 2: 8 tiles; each wave filters its own query by s <= T (knn4-identical logic)
  for(int tt=0;tt<8;++tt){
    if (tt>0){
      __syncthreads();   // all waves done scanning previous tile
      const int i = threadIdx.x;
      ((float4*)tx)[i] = ((const float4*)xs)[tt*256 + i];
      ((float4*)ty)[i] = ((const float4*)ys)[tt*256 + i];
      ((float4*)tz)[i] = ((const float4*)zs)[tt*256 + i];
      ((float4*)tq)[i] = ((const float4*)qs)[tt*256 + i];
      __syncthreads();   // tile ready
    }
    for(int c=0;c<4;++c){
      const int fi = c*64 + lane;
      const int base = tt*1024 + fi*4;
      const float4 fx = ((const float4*)tx)[fi];
      const float4 fy = ((const float4*)ty)[fi];
      const float4 fz = ((const float4*)tz)[fi];
      const float4 fq = ((const float4*)tq)[fi];
      float ss[4];
      ss[0] = fmaf(-px,fx.x, fmaf(-py,fy.x, fmaf(-pz,fz.x, fq.x)));
      ss[1] = fmaf(-px,fx.y, fmaf(-py,fy.y, fmaf(-pz,fz.y, fq.y)));
      ss[2] = fmaf(-px,fx.z, fmaf(-py,fy.z, fmaf(-pz,fz.z, fq.z)));
      ss[3] = fmaf(-px,fx.w, fmaf(-py,fy.w, fmaf(-pz,fz.w, fq.w)));
      #pragma unroll
      for(int q=0;q<4;++q){
        if (ss[q] <= T){
          int pos = atomicAdd(&scount[w],1);
          if (pos < KNN_CAP){ sdist[w][pos]=ss[q]; sidx[w][pos]=base+q; }
        }
      }
    }
  }
  __syncthreads();

  // Phase 3 (knn4-identical): exact top-9 over own survivors, (s,id)-lexicographic
  int m = scount[w]; if (m > KNN_CAP) m = KNN_CAP;
  float dl[KNN_CAP/64]; int il[KNN_CAP/64];
  #pragma unroll
  for(int k=0;k<KNN_CAP/64;++k){
    const int j = lane + 64*k;
    if (j < m){ dl[k]=sdist[w][j]; il[k]=sidx[w][j]; }
    else      { dl[k]=INFINITY;    il[k]=0x7fffffff; }
  }
  for(int r=0;r<9;++r){
    float bv=dl[0]; int bi=il[0];
    #pragma unroll
    for(int k=1;k<KNN_CAP/64;++k){
      if (dl[k]<bv || (dl[k]==bv && il[k]<bi)){ bv=dl[k]; bi=il[k]; }
    }
    float v=bv; int ix=bi;
    #pragma unroll
    for(int s=32;s>0;s>>=1){
      float ov=__shfl_xor(v,s,64); int oi=__shfl_xor(ix,s,64);
      if (ov<v || (ov==v && oi<ix)){ v=ov; ix=oi; }
    }
    if (ix != node && lane==0){
      int cpos = atomicAdd(&cnt[ix],1);
      if (cpos < REV_CAP) rev[ix*REV_CAP + cpos] = node;
    }
    #pragma unroll
    for(int k=0;k<KNN_CAP/64;++k){
      if (il[k]==ix){ dl[k]=INFINITY; il[k]=0x7fffffff; }
    }
  }
}

// =================== moment-based message passing: LDS-staged parallel edge geometry (r10 verbatim) ===================
__global__ __launch_bounds__(256) void k_msg(
  const float* __restrict__ pos,
  const int* __restrict__ cnt, const int* __restrict__ rev,
  const float* __restrict__ Kbuf,
  const float* __restrict__ xf,
  const float* __restrict__ tpw,
  const float* __restrict__ W0, const float* __restrict__ W1, const float* __restrict__ W2,
  float* __restrict__ yf)
{
  const int t = threadIdx.x;
  const int w = t >> 6;
  const int lane = t & 63;
  const int n = blockIdx.x*4 + w;

  __shared__ float KL[405];
  __shared__ float TW[144];
  __shared__ float momP[4][120];
  __shared__ float momS[4][600];
  __shared__ float aS[4][480];
  __shared__ int   eIdx[4][REV_CAP];
  __shared__ float eSh[4][5][REV_CAP];
  for(int q=t;q<405;q+=256) KL[q]=Kbuf[q];
  for(int q=t;q<144;q+=256) TW[q]=tpw[q];

  // Stage 1a: parallel edge geometry (lane e < deg owns edge e)
  const int deg0 = cnt[n];
  const int deg = (deg0<REV_CAP)? deg0 : REV_CAP;
  const float pnx=pos[3*n], pny=pos[3*n+1], pnz=pos[3*n+2];
  const float s15 = 3.8729833462f, s5c = 2.2360679775f;
  if (lane < deg){
    const int i = rev[n*REV_CAP+lane];
    eIdx[w][lane] = i;
    const float ex = pnx - pos[3*i], ey = pny - pos[3*i+1], ez = pnz - pos[3*i+2];
    const float rn = sqrtf(ex*ex+ey*ey+ez*ez) + 1e-12f;
    const float ux=ex/rn, uy=ey/rn, uz=ez/rn;
    eSh[w][0][lane]=s15*ux*uy;
    eSh[w][1][lane]=s15*uy*uz;
    eSh[w][2][lane]=0.5f*s5c*(3.f*uz*uz-1.f);
    eSh[w][3][lane]=s15*ux*uz;
    eSh[w][4][lane]=0.5f*s15*(ux*ux-uy*uy);
  }
  __syncthreads();

  // Stage 1b: moment accumulation (lane owns 2 feature components; edge data from LDS)
  const int c0 = lane*2;
  float mp0=0.f, mp1=0.f;
  float ms0[5], ms1[5];
  #pragma unroll
  for(int j=0;j<5;++j){ ms0[j]=0.f; ms1[j]=0.f; }
  for(int e=0;e<deg;++e){
    const int i = eIdx[w][e];
    const float sh0=eSh[w][0][e], sh1=eSh[w][1][e], sh2=eSh[w][2][e];
    const float sh3=eSh[w][3][e], sh4=eSh[w][4][e];
    if (lane<60){
      const float2 f = *(const float2*)(xf + (size_t)i*120 + c0);
      mp0 += f.x; mp1 += f.y;
      ms0[0]+=f.x*sh0; ms0[1]+=f.x*sh1; ms0[2]+=f.x*sh2; ms0[3]+=f.x*sh3; ms0[4]+=f.x*sh4;
      ms1[0]+=f.y*sh0; ms1[1]+=f.y*sh1; ms1[2]+=f.y*sh2; ms1[3]+=f.y*sh3; ms1[4]+=f.y*sh4;
    }
  }
  if (lane<60){
    momP[w][c0]=mp0; momP[w][c0+1]=mp1;
    #pragma unroll
    for(int j=0;j<5;++j){ momS[w][c0*5+j]=ms0[j]; momS[w][(c0+1)*5+j]=ms1[j]; }
  }
  __syncthreads();

  // Stage 2: per-node K-contraction on moments
  float acc[14];
  #pragma unroll
  for(int k=0;k<14;++k) acc[k]=0.f;

  if (lane<32){
    const int u=lane;
    const float rw0=TW[u], rw1=TW[32+u];
    acc[0] = rw0 * KL[0] * momP[w][u];                       // p1
    float m0s[5];
    #pragma unroll
    for(int j=0;j<5;++j) m0s[j]=momS[w][u*5+j];
    #pragma unroll
    for(int o=0;o<5;++o){ float g=0.f;                       // p2
      #pragma unroll
      for(int j=0;j<5;++j) g += KL[1+o*5+j]*m0s[j];
      acc[1+o] = rw1*g; }
  } else if (lane<48){
    const int u=lane-32;
    const float rw0=TW[64+u], rw1=TW[80+u], rw2=TW[96+u];
    float m1p[3], m1s[3][5];
    #pragma unroll
    for(int i=0;i<3;++i){
      m1p[i]=momP[w][32+u*3+i];
      #pragma unroll
      for(int j=0;j<5;++j) m1s[i][j]=momS[w][(32+u*3+i)*5+j];
    }
    #pragma unroll
    for(int o=0;o<3;++o){ float g=0.f;                       // p3
      #pragma unroll
      for(int i=0;i<3;++i) g += KL[26+o*3+i]*m1p[i];
      acc[o]=rw0*g; }
    #pragma unroll
    for(int o=0;o<3;++o){ float g=0.f;                       // p4
      #pragma unroll
      for(int i=0;i<3;++i)
        #pragma unroll
        for(int j=0;j<5;++j) g += KL[35+(o*3+i)*5+j]*m1s[i][j];
      acc[3+o]=rw1*g; }
    #pragma unroll
    for(int o=0;o<5;++o){ float g=0.f;                       // p5
      #pragma unroll
      for(int i=0;i<3;++i)
        #pragma unroll
        for(int j=0;j<5;++j) g += KL[80+(o*3+i)*5+j]*m1s[i][j];
      acc[6+o]=rw2*g; }
  } else if (lane<56){
    const int u=lane-48;
    const float rw0=TW[112+u], rw1=TW[120+u], rw2=TW[128+u], rw3=TW[136+u];
    float m2p[5], m2s[5][5];
    #pragma unroll
    for(int i=0;i<5;++i){
      m2p[i]=momP[w][80+u*5+i];
      #pragma unroll
      for(int j=0;j<5;++j) m2s[i][j]=momS[w][(80+u*5+i)*5+j];
    }
    #pragma unroll
    for(int o=0;o<5;++o){ float g=0.f;                       // p6
      #pragma unroll
      for(int i=0;i<5;++i) g += KL[155+o*5+i]*m2p[i];
      acc[o]=rw0*g; }
    { float g=0.f;                                           // p7
      #pragma unroll
      for(int i=0;i<5;++i)
        #pragma unroll
        for(int j=0;j<5;++j) g += KL[180+i*5+j]*m2s[i][j];
      acc[5]=rw1*g; }
    #pragma unroll
    for(int o=0;o<3;++o){ float g=0.f;                       // p8
      #pragma unroll
      for(int i=0;i<5;++i)
        #pragma unroll
        for(int j=0;j<5;++j) g += KL[205+(o*5+i)*5+j]*m2s[i][j];
      acc[6+o]=rw2*g; }
    #pragma unroll
    for(int o=0;o<5;++o){ float g=0.f;                       // p9
      #pragma unroll
      for(int i=0;i<5;++i)
        #pragma unroll
        for(int j=0;j<5;++j) g += KL[280+(o*5+i)*5+j]*m2s[i][j];
      acc[9+o]=rw3*g; }
  }

  // scatter into aS: concat m0=[p1,p7], m1=[p3,p4,p8], m2=[p2,p5,p6,p9]
  if (lane<32){
    aS[w][lane] = acc[0];
    #pragma unroll
    for(int o=0;o<5;++o) aS[w][160 + lane*5+o] = acc[1+o];
  } else if (lane<48){
    const int uu=lane-32;
    #pragma unroll
    for(int m=0;m<3;++m){ aS[w][40 + uu*3+m] = acc[m]; aS[w][40 + (16+uu)*3+m] = acc[3+m]; }
    #pragma unroll
    for(int o=0;o<5;++o) aS[w][160 + (32+uu)*5+o] = acc[6+o];
  } else if (lane<56){
    const int uu=lane-48;
    aS[w][32+uu] = acc[5];
    #pragma unroll
    for(int m=0;m<3;++m) aS[w][40 + (32+uu)*3+m] = acc[6+m];
    #pragma unroll
    for(int o=0;o<5;++o){ aS[w][160 + (48+uu)*5+o] = acc[o]; aS[w][160 + (56+uu)*5+o] = acc[9+o]; }
  }
  __syncthreads();

  // Stage 3: linear mixes, write yf[n][120]
  const float inv40 = 0.15811388300841896660f;
  for(int q=lane;q<120;q+=64){
    float out;
    if (q<32){
      float g=0.f;
      for(int uu=0;uu<40;++uu) g += aS[w][uu]*W0[uu*32+q];
      out = g*inv40;
    } else if (q<80){
      const int e=q-32, v=e/3, m=e%3;
      float g=0.f;
      for(int uu=0;uu<40;++uu) g += aS[w][40+uu*3+m]*W1[uu*16+v];
      out = g*inv40;
    } else {
      const int e=q-80, tt=e/5, m=e%5;
      float g=0.f;
      for(int uu=0;uu<64;++uu) g += aS[w][160+uu*5+m]*W2[uu*8+tt];
      out = g*0.125f;
    }
    yf[(size_t)n*120+q] = out;
  }
}

// =================== stats partials: 96 ch x 8 chunks, deterministic disjoint writes ===================
__global__ __launch_bounds__(256) void k_statp(const float* __restrict__ yf,
                                               float* __restrict__ pA, float* __restrict__ pB){
  const int ch = blockIdx.x % 96;
  const int chunk = blockIdx.x / 96;
  const int t = threadIdx.x;
  const int n0 = chunk*1024;
  __shared__ float r1[256], r2[256];
  float a1=0.f, a2=0.f;
  if (ch<32){
    for(int nn=t;nn<1024;nn+=256){ float v=yf[(size_t)(n0+nn)*120+ch]; a1+=v; a2+=v*v; }
  } else if (ch<48){
    const int v_=ch-32;
    for(int nn=t;nn<1024;nn+=256){
      #pragma unroll
      for(int m=0;m<3;++m){ float v=yf[(size_t)(n0+nn)*120+32+v_*3+m]; a2+=v*v; }
    }
  } else {
    const int t_=ch-48;
    for(int nn=t;nn<1024;nn+=256){
      #pragma unroll
      for(int m=0;m<5;++m){ float v=yf[(size_t)(n0+nn)*120+80+t_*5+m]; a2+=v*v; }
    }
  }
  r1[t]=a1; r2[t]=a2; __syncthreads();
  for(int s=128;s>0;s>>=1){ if(t<s){ r1[t]+=r1[t+s]; r2[t]+=r2[t+s]; } __syncthreads(); }
  if(t==0){ pA[ch*8+chunk]=r1[0]; pB[ch*8+chunk]=r2[0]; }
}

// =================== normalize + relu + residual (layers 0,1): per-block finalize + apply ===================
__global__ __launch_bounds__(256) void k_norm(const float* __restrict__ yf,
                       const float* __restrict__ pA, const float* __restrict__ pB,
                       const float* __restrict__ bw0,const float* __restrict__ bb0,
                       const float* __restrict__ bw1,const float* __restrict__ bw2,
                       float* __restrict__ xf){
  __shared__ float sc[96], sf[32];
  const int t = threadIdx.x;
  if (t<96){
    float sB=0.f;
    #pragma unroll
    for(int k=0;k<8;++k) sB += pB[t*8+k];
    float scale;
    if (t<32){
      float sA=0.f;
      #pragma unroll
      for(int k=0;k<8;++k) sA += pA[t*8+k];
      const float mean = sA*(1.f/8192.f);
      const float var  = sB*(1.f/8192.f) - mean*mean;
      const float inv  = 1.f/sqrtf(var+1e-5f);
      scale = bw0[t]*inv;
      sf[t] = bb0[t] - mean*scale;
    } else if (t<48){
      scale = bw1[t-32]/sqrtf(sB*(1.f/(8192.f*3.f))+1e-5f);
    } else {
      scale = bw2[t-48]/sqrtf(sB*(1.f/(8192.f*5.f))+1e-5f);
    }
    sc[t]=scale;
  }
  __syncthreads();
  const int idx = blockIdx.x*256 + t;
  if (idx >= NN*120) return;
  const int c = idx%120;
  const int chan = (c<32)? c : ((c<80)? 32+(c-32)/3 : 48+(c-80)/5);
  const float v = yf[idx]*sc[chan] + ((c<32)? sf[c] : 0.f);
  xf[idx] += fmaxf(v,0.f);
}

// =================== fused layer-3 norm (x0 only; l1/l2 dead) + final MLP ===================
__global__ __launch_bounds__(256) void k_normmlp(const float* __restrict__ yf,
                                             const float* __restrict__ xf,
                                             const float* __restrict__ pA, const float* __restrict__ pB,
                                             const float* __restrict__ bw0,const float* __restrict__ bb0,
                                             const float* __restrict__ Wf1,const float* __restrict__ Wf2,
                                             const float* __restrict__ bf2,const float* __restrict__ Wf3,
                                             const float* __restrict__ bf3, float* __restrict__ out){
  __shared__ float w1[1024], w2[512], w3[32], b2[16], b3[2], sc0[32], sf0[32];
  const int t=threadIdx.x;
  for(int q=t;q<1024;q+=256) w1[q]=Wf1[q];
  for(int q=t;q<512;q+=256)  w2[q]=Wf2[q];
  if(t<32) w3[t]=Wf3[t];
  if(t<16) b2[t]=bf2[t];
  if(t<2)  b3[t]=bf3[t];
  if(t<32){
    float sA=0.f, sB=0.f;
    #pragma unroll
    for(int k=0;k<8;++k){ sA += pA[t*8+k]; sB += pB[t*8+k]; }
    const float mean = sA*(1.f/8192.f);
    const float var  = sB*(1.f/8192.f) - mean*mean;
    const float inv  = 1.f/sqrtf(var+1e-5f);
    sc0[t] = bw0[t]*inv;
    sf0[t] = bb0[t] - mean*sc0[t];
  }
  __syncthreads();
  const int n = blockIdx.x*256+t;
  if(n>=NN) return;
  float xv[32];
  #pragma unroll
  for(int k=0;k<32;++k){
    const float v = yf[(size_t)n*120+k]*sc0[k] + sf0[k];
    xv[k] = xf[(size_t)n*120+k] + fmaxf(v,0.f);
  }
  const float inv32 = 0.17677669529663688110f;
  float h1[32];
  #pragma unroll 4
  for(int c=0;c<32;++c){ float g=0.f;
    #pragma unroll
    for(int k=0;k<32;++k) g+=xv[k]*w1[k*32+c];
    h1[c]=fmaxf(g*inv32,0.f); }
  float h2[16];
  #pragma unroll 4
  for(int c=0;c<16;++c){ float g=b2[c];
    #pragma unroll
    for(int k=0;k<32;++k) g+=h1[k]*w2[k*16+c];
    h2[c]=fmaxf(g,0.f); }
  #pragma unroll
  for(int m=0;m<2;++m){ float g=b3[m];
    #pragma unroll
    for(int k=0;k<16;++k) g+=h2[k]*w3[k*2+m];
    out[n*2+m]=g; }
}

extern "C" void kernel_launch(void* const* d_in, const int* in_sizes, int n_in,
                              void* d_out, int out_size, void* d_ws, size_t ws_size,
                              hipStream_t stream) {
  const float* positions = (const float*)d_in[0];
  const float* W_emb  = (const float*)d_in[1];
  const float* tp_w   = (const float*)d_in[2];
  const float* lin_W0 = (const float*)d_in[3];
  const float* lin_W1 = (const float*)d_in[4];
  const float* lin_W2 = (const float*)d_in[5];
  const float* bn_w0  = (const float*)d_in[6];
  const float* bn_b0  = (const float*)d_in[7];
  const float* bn_w1  = (const float*)d_in[8];
  const float* bn_w2  = (const float*)d_in[9];
  const float* Wf1 = (const float*)d_in[10];
  const float* Wf2 = (const float*)d_in[11];
  const float* bf2 = (const float*)d_in[12];
  const float* Wf3 = (const float*)d_in[13];
  const float* bf3 = (const float*)d_in[14];

  if (ws_size < WS_FLOATS*sizeof(float)) return;

  float* ws    = (float*)d_ws;
  float* Kbuf  = ws + OFF_K;
  int*   cnt   = (int*)(ws + OFF_CNT);
  int*   rev   = (int*)(ws + OFF_REV);
  float* stats = ws + OFF_STATS;   // 3 layers x (768 pA | 768 pB)
  float* xf = ws + OFF_XF;
  float* yf = ws + OFF_YF;

  // SoA position arrays alias the head of yf (dead after k_knn6; first k_msg rewrites yf)
  float* xs = yf;
  float* ysA = yf + NN;
  float* zs = yf + 2*NN;
  float* qs = yf + 3*NN;

  k_setup<<<3906,256,0,stream>>>(positions, W_emb, Kbuf, xf, xs, ysA, zs, qs, cnt);
  k_knn6<<<NN/4,256,0,stream>>>(xs, ysA, zs, qs, cnt, rev);

  for(int l=0;l<3;++l){
    float* pA = stats + l*1536;
    float* pB = pA + 768;
    k_msg<<<NN/4,256,0,stream>>>(positions, cnt, rev, Kbuf, xf,
                              tp_w + l*144, lin_W0 + l*40*32, lin_W1 + l*40*16, lin_W2 + l*64*8,
                              yf);
    k_statp<<<768,256,0,stream>>>(yf, pA, pB);
    if (l<2){
      k_norm<<<(NN*120+255)/256,256,0,stream>>>(yf, pA, pB,
                              bn_w0 + l*32, bn_b0 + l*32, bn_w1 + l*16, bn_w2 + l*8,
                              xf);
    }
  }
  k_normmlp<<<NN/256,256,0,stream>>>(yf, xf, stats + 2*1536, stats + 2*1536 + 768,
                              bn_w0 + 64, bn_b0 + 64,
                              Wf1, Wf2, bf2, Wf3, bf3, (float*)d_out);
}

// Round 14
// 309.999 us; speedup vs baseline: 3.7425x; 1.0339x over previous
//
#include <hip/hip_runtime.h>
#include <math.h>

#define NN 8192
#define REV_CAP 48
#define KNN_CAP 256   // per-wave survivor cap (2048-sample bound -> E[survivors]~36; P(overflow)<1e-20)
#define PF 12         // k_msg edge-gather prefetch depth

// ---- ws layout (float element offsets) ----
static const size_t OFF_K     = 0;        // 405
static const size_t OFF_CNT   = 512;      // int[8192]
static const size_t OFF_REV   = 8704;     // int[8192*48]
static const size_t OFF_STATS = 401920;   // 3 layers x (768 A-partials + 768 B-partials)
static const size_t OFF_XF    = 406528;   // 8192*120 interleaved features
static const size_t OFF_YF    = 1389568;  // 8192*120 outputs (head aliased as SoA x/y/z/q for KNN)
static const size_t WS_FLOATS = 2372608;

// =================== K tensor math (device, double precision) ===================
__device__ double dfact(int n){ double r=1.0; for(int i=2;i<=n;++i) r*=(double)i; return r; }

__device__ double dcg(int j1,int m1,int j2,int m2,int j3,int m3){
  if (m1+m2!=m3) return 0.0;
  if (j3 < abs(j1-j2) || j3 > j1+j2) return 0.0;
  double pre = sqrt((double)(2*j3+1)*dfact(j3+j1-j2)*dfact(j3-j1+j2)*dfact(j1+j2-j3)/dfact(j1+j2+j3+1));
  pre *= sqrt(dfact(j3+m3)*dfact(j3-m3)*dfact(j1-m1)*dfact(j1+m1)*dfact(j2-m2)*dfact(j2+m2));
  double s=0.0;
  for(int k=0;k<=j1+j2-j3;++k){
    int d1=j1+j2-j3-k, d2=j1-m1-k, d3=j2+m2-k, d4=j3-j2+m1+k, d5=j3-j1-m2+k;
    if(d1<0||d2<0||d3<0||d4<0||d5<0) continue;
    double den = dfact(k)*dfact(d1)*dfact(d2)*dfact(d3)*dfact(d4)*dfact(d5);
    s += ((k&1)? -1.0: 1.0)/den;
  }
  return pre*s;
}

__device__ int qrow(int l,int r,int* col,double* re,double* im){
  const double s = 0.70710678118654752440;
  if (r==l){ col[0]=l; re[0]=1.0; im[0]=0.0; return 1; }
  if (r>l){ int m=r-l;
    col[0]=l+m; re[0]=((m&1)?-s:s); im[0]=0.0;
    col[1]=l-m; re[1]=s;            im[1]=0.0;
  } else { int m=l-r;
    col[0]=l+m; re[0]=0.0; im[0]=((m&1)? s : -s);
    col[1]=l-m; re[1]=0.0; im[1]=s;
  }
  return 2;
}

// =================== fused setup: xf init | SoA+q | cnt | K ===================
__global__ __launch_bounds__(256) void k_setup(const float* __restrict__ pos,
        const float* __restrict__ W_emb, float* __restrict__ Kbuf,
        float* __restrict__ xf,
        float* __restrict__ xs, float* __restrict__ ys, float* __restrict__ zs,
        float* __restrict__ qs,
        int* __restrict__ cnt){
  int idx = blockIdx.x*256 + threadIdx.x;
  if (idx < 983040) { const int c = idx%120; xf[idx] = (c<32)? W_emb[c] : 0.f; return; }
  idx -= 983040;
  if (idx < 8192) {
    const float x=pos[3*idx], y=pos[3*idx+1], z=pos[3*idx+2];
    xs[idx]=x; ys[idx]=y; zs[idx]=z; qs[idx]=0.5f*(x*x+y*y+z*z);
    return;
  }
  idx -= 8192;
  if (idx < 8192) { cnt[idx]=0; return; }
  idx -= 8192;
  if (idx >= 405) return;

  const int tid = idx;
  const int sizes[9]={1,25,9,45,75,25,25,75,125};
  const int l1s[9]={0,0,1,1,1,2,2,2,2};
  const int l2s[9]={0,2,0,2,2,0,2,2,2};
  const int l3s[9]={0,2,1,1,2,2,0,1,2};
  int p=0, rem=tid;
  for(p=0;p<9;++p){ if(rem < sizes[p]) break; rem -= sizes[p]; }
  const int l1=l1s[p], l2=l2s[p], l3=l3s[p];
  const int n1=2*l1+1, n2=2*l2+1;
  const int c = rem/(n1*n2); const int r2 = rem%(n1*n2); const int a=r2/n2; const int b=r2%n2;

  int c3[2],c1[2],c2[2]; double re3[2],im3[2],re1[2],im1[2],re2[2],im2[2];
  const int nc3 = qrow(l3,c,c3,re3,im3);
  const int nc1 = qrow(l1,a,c1,re1,im1);
  const int nc2 = qrow(l2,b,c2,re2,im2);

  double accRe=0, accIm=0;
  for(int i3=0;i3<nc3;++i3){
    const double q3re=re3[i3], q3im=-im3[i3];
    for(int i1=0;i1<nc1;++i1){
      const double pre_re = q3re*re1[i1] - q3im*im1[i1];
      const double pre_im = q3re*im1[i1] + q3im*re1[i1];
      for(int i2=0;i2<nc2;++i2){
        const double cgv = dcg(l1, c1[i1]-l1, l2, c2[i2]-l2, l3, c3[i3]-l3);
        if (cgv==0.0) continue;
        accRe += (pre_re*re2[i2] - pre_im*im2[i2])*cgv;
        accIm += (pre_re*im2[i2] + pre_im*re2[i2])*cgv;
      }
    }
  }
  const bool useImag = ((l1+l2+l3)&1)!=0;
  Kbuf[tid] = (float)(useImag? accIm : accRe);
}

// =================== exact 9-NN: knn4 skeleton, 2048-sample bound, CAP 256 ===================
__global__ __launch_bounds__(256) void k_knn7(const float* __restrict__ xs,
                                              const float* __restrict__ ys,
                                              const float* __restrict__ zs,
                                              const float* __restrict__ qs,
                                              int* __restrict__ cnt, int* __restrict__ rev){
  const int lane = threadIdx.x & 63;
  const int w    = threadIdx.x >> 6;
  const int node = blockIdx.x*4 + w;
  __shared__ float sdist[4][KNN_CAP];
  __shared__ int   sidx[4][KNN_CAP];
  __shared__ int   scount[4];
  if (threadIdx.x < 4) scount[threadIdx.x]=0;
  __syncthreads();

  const float px = xs[node], py = ys[node], pz = zs[node];

  // Phase 1 (knn4-identical math, sample=2048): per-lane top-2 -> bound T
  float m1 = INFINITY, m2 = INFINITY;
  for(int c=0;c<8;++c){
    const int base = (c*64 + lane)*4;
    const float4 fx = *(const float4*)(xs + base);
    const float4 fy = *(const float4*)(ys + base);
    const float4 fz = *(const float4*)(zs + base);
    const float4 fq = *(const float4*)(qs + base);
    float ss[4];
    ss[0] = fmaf(-px,fx.x, fmaf(-py,fy.x, fmaf(-pz,fz.x, fq.x)));
    ss[1] = fmaf(-px,fx.y, fmaf(-py,fy.y, fmaf(-pz,fz.y, fq.y)));
    ss[2] = fmaf(-px,fx.z, fmaf(-py,fy.z, fmaf(-pz,fz.z, fq.z)));
    ss[3] = fmaf(-px,fx.w, fmaf(-py,fy.w, fmaf(-pz,fz.w, fq.w)));
    #pragma unroll
    for(int q=0;q<4;++q){
      const float hi = fmaxf(m1, ss[q]);
      m1 = fminf(m1, ss[q]);
      m2 = fminf(m2, hi);
    }
  }
  float T = INFINITY;
  for(int r=0;r<9;++r){
    float v = m1; int l = lane;
    #pragma unroll
    for(int s=32;s>0;s>>=1){
      const float ov=__shfl_xor(v,s,64); const int ol=__shfl_xor(l,s,64);
      if (ov<v || (ov==v && ol<l)){ v=ov; l=ol; }
    }
    T = v;
    if (lane==l){ m1=m2; m2=INFINITY; }
  }

  // Phase 2 (knn4-identical): filter all 8192 candidates by s <= T
  for(int c=0;c<32;++c){
    const int base = (c*64 + lane)*4;
    const float4 fx = *(const float4*)(xs + base);
    const float4 fy = *(const float4*)(ys + base);
    const float4 fz = *(const float4*)(zs + base);
    const float4 fq = *(const float4*)(qs + base);
    float ss[4];
    ss[0] = fmaf(-px,fx.x, fmaf(-py,fy.x, fmaf(-pz,fz.x, fq.x)));
    ss[1] = fmaf(-px,fx.y, fmaf(-py,fy.y, fmaf(-pz,fz.y, fq.y)));
    ss[2] = fmaf(-px,fx.z, fmaf(-py,fy.z, fmaf(-pz,fz.z, fq.z)));
    ss[3] = fmaf(-px,fx.w, fmaf(-py,fy.w, fmaf(-pz,fz.w, fq.w)));
    #pragma unroll
    for(int q=0;q<4;++q){
      if (ss[q] <= T){
        int pos = atomicAdd(&scount[w],1);
        if (pos < KNN_CAP){ sdist[w][pos]=ss[q]; sidx[w][pos]=base+q; }
      }
    }
  }
  __syncthreads();

  // Phase 3 (knn4-identical): exact top-9 over survivors, (s,id)-lexicographic
  int m = scount[w]; if (m > KNN_CAP) m = KNN_CAP;
  float dl[KNN_CAP/64]; int il[KNN_CAP/64];
  #pragma unroll
  for(int k=0;k<KNN_CAP/64;++k){
    const int j = lane + 64*k;
    if (j < m){ dl[k]=sdist[w][j]; il[k]=sidx[w][j]; }
    else      { dl[k]=INFINITY;    il[k]=0x7fffffff; }
  }
  for(int r=0;r<9;++r){
    float bv=dl[0]; int bi=il[0];
    #pragma unroll
    for(int k=1;k<KNN_CAP/64;++k){
      if (dl[k]<bv || (dl[k]==bv && il[k]<bi)){ bv=dl[k]; bi=il[k]; }
    }
    float v=bv; int ix=bi;
    #pragma unroll
    for(int s=32;s>0;s>>=1){
      float ov=__shfl_xor(v,s,64); int oi=__shfl_xor(ix,s,64);
      if (ov<v || (ov==v && oi<ix)){ v=ov; ix=oi; }
    }
    if (ix != node && lane==0){
      int cpos = atomicAdd(&cnt[ix],1);
      if (cpos < REV_CAP) rev[ix*REV_CAP + cpos] = node;
    }
    #pragma unroll
    for(int k=0;k<KNN_CAP/64;++k){
      if (il[k]==ix){ dl[k]=INFINITY; il[k]=0x7fffffff; }
    }
  }
}

// =================== moment-based message passing: prefetched edge gathers ===================
// r10/r13 proven body; stage 1b restructured to issue up to PF independent xf loads
// before consuming (compile-time-unrolled register array, wave-uniform guards).
__global__ __launch_bounds__(256) void k_msg(
  const float* __restrict__ pos,
  const int* __restrict__ cnt, const int* __restrict__ rev,
  const float* __restrict__ Kbuf,
  const float* __restrict__ xf,
  const float* __restrict__ tpw,
  const float* __restrict__ W0, const float* __restrict__ W1, const float* __restrict__ W2,
  float* __restrict__ yf)
{
  const int t = threadIdx.x;
  const int w = t >> 6;
  const int lane = t & 63;
  const int n = blockIdx.x*4 + w;

  __shared__ float KL[405];
  __shared__ float TW[144];
  __shared__ float momP[4][120];
  __shared__ float momS[4][600];
  __shared__ float aS[4][480];
  __shared__ int   eIdx[4][REV_CAP];
  __shared__ float eSh[4][5][REV_CAP];
  for(int q=t;q<405;q+=256) KL[q]=Kbuf[q];
  for(int q=t;q<144;q+=256) TW[q]=tpw[q];

  // Stage 1a: parallel edge geometry (lane e < deg owns edge e)
  const int deg0 = cnt[n];
  const int deg = (deg0<REV_CAP)? deg0 : REV_CAP;
  const float pnx=pos[3*n], pny=pos[3*n+1], pnz=pos[3*n+2];
  const float s15 = 3.8729833462f, s5c = 2.2360679775f;
  if (lane < deg){
    const int i = rev[n*REV_CAP+lane];
    eIdx[w][lane] = i;
    const float ex = pnx - pos[3*i], ey = pny - pos[3*i+1], ez = pnz - pos[3*i+2];
    const float rn = sqrtf(ex*ex+ey*ey+ez*ez) + 1e-12f;
    const float ux=ex/rn, uy=ey/rn, uz=ez/rn;
    eSh[w][0][lane]=s15*ux*uy;
    eSh[w][1][lane]=s15*uy*uz;
    eSh[w][2][lane]=0.5f*s5c*(3.f*uz*uz-1.f);
    eSh[w][3][lane]=s15*ux*uz;
    eSh[w][4][lane]=0.5f*s15*(ux*ux-uy*uy);
  }
  __syncthreads();

  // Stage 1b: moment accumulation with prefetched gathers
  const int c0 = lane*2;
  float mp0=0.f, mp1=0.f;
  float ms0[5], ms1[5];
  #pragma unroll
  for(int j=0;j<5;++j){ ms0[j]=0.f; ms1[j]=0.f; }

  // prefetch indices (safe 0-fill beyond deg), then issue all loads
  int idxr[PF];
  #pragma unroll
  for(int k=0;k<PF;++k) idxr[k] = (k<deg)? eIdx[w][k] : 0;
  float2 fr[PF];
  if (lane<60){
    #pragma unroll
    for(int k=0;k<PF;++k) fr[k] = *(const float2*)(xf + (size_t)idxr[k]*120 + c0);
  }
  #pragma unroll
  for(int k=0;k<PF;++k){
    if (k<deg){
      const float sh0=eSh[w][0][k], sh1=eSh[w][1][k], sh2=eSh[w][2][k];
      const float sh3=eSh[w][3][k], sh4=eSh[w][4][k];
      if (lane<60){
        const float2 f = fr[k];
        mp0 += f.x; mp1 += f.y;
        ms0[0]+=f.x*sh0; ms0[1]+=f.x*sh1; ms0[2]+=f.x*sh2; ms0[3]+=f.x*sh3; ms0[4]+=f.x*sh4;
        ms1[0]+=f.y*sh0; ms1[1]+=f.y*sh1; ms1[2]+=f.y*sh2; ms1[3]+=f.y*sh3; ms1[4]+=f.y*sh4;
      }
    }
  }
  for(int e=PF;e<deg;++e){   // rare tail (deg>PF)
    const int i = eIdx[w][e];
    const float sh0=eSh[w][0][e], sh1=eSh[w][1][e], sh2=eSh[w][2][e];
    const float sh3=eSh[w][3][e], sh4=eSh[w][4][e];
    if (lane<60){
      const float2 f = *(const float2*)(xf + (size_t)i*120 + c0);
      mp0 += f.x; mp1 += f.y;
      ms0[0]+=f.x*sh0; ms0[1]+=f.x*sh1; ms0[2]+=f.x*sh2; ms0[3]+=f.x*sh3; ms0[4]+=f.x*sh4;
      ms1[0]+=f.y*sh0; ms1[1]+=f.y*sh1; ms1[2]+=f.y*sh2; ms1[3]+=f.y*sh3; ms1[4]+=f.y*sh4;
    }
  }
  if (lane<60){
    momP[w][c0]=mp0; momP[w][c0+1]=mp1;
    #pragma unroll
    for(int j=0;j<5;++j){ momS[w][c0*5+j]=ms0[j]; momS[w][(c0+1)*5+j]=ms1[j]; }
  }
  __syncthreads();

  // Stage 2: per-node K-contraction on moments (r9/r10 verbatim)
  float acc[14];
  #pragma unroll
  for(int k=0;k<14;++k) acc[k]=0.f;

  if (lane<32){
    const int u=lane;
    const float rw0=TW[u], rw1=TW[32+u];
    acc[0] = rw0 * KL[0] * momP[w][u];                       // p1
    float m0s[5];
    #pragma unroll
    for(int j=0;j<5;++j) m0s[j]=momS[w][u*5+j];
    #pragma unroll
    for(int o=0;o<5;++o){ float g=0.f;                       // p2
      #pragma unroll
      for(int j=0;j<5;++j) g += KL[1+o*5+j]*m0s[j];
      acc[1+o] = rw1*g; }
  } else if (lane<48){
    const int u=lane-32;
    const float rw0=TW[64+u], rw1=TW[80+u], rw2=TW[96+u];
    float m1p[3], m1s[3][5];
    #pragma unroll
    for(int i=0;i<3;++i){
      m1p[i]=momP[w][32+u*3+i];
      #pragma unroll
      for(int j=0;j<5;++j) m1s[i][j]=momS[w][(32+u*3+i)*5+j];
    }
    #pragma unroll
    for(int o=0;o<3;++o){ float g=0.f;                       // p3
      #pragma unroll
      for(int i=0;i<3;++i) g += KL[26+o*3+i]*m1p[i];
      acc[o]=rw0*g; }
    #pragma unroll
    for(int o=0;o<3;++o){ float g=0.f;                       // p4
      #pragma unroll
      for(int i=0;i<3;++i)
        #pragma unroll
        for(int j=0;j<5;++j) g += KL[35+(o*3+i)*5+j]*m1s[i][j];
      acc[3+o]=rw1*g; }
    #pragma unroll
    for(int o=0;o<5;++o){ float g=0.f;                       // p5
      #pragma unroll
      for(int i=0;i<3;++i)
        #pragma unroll
        for(int j=0;j<5;++j) g += KL[80+(o*3+i)*5+j]*m1s[i][j];
      acc[6+o]=rw2*g; }
  } else if (lane<56){
    const int u=lane-48;
    const float rw0=TW[112+u], rw1=TW[120+u], rw2=TW[128+u], rw3=TW[136+u];
    float m2p[5], m2s[5][5];
    #pragma unroll
    for(int i=0;i<5;++i){
      m2p[i]=momP[w][80+u*5+i];
      #pragma unroll
      for(int j=0;j<5;++j) m2s[i][j]=momS[w][(80+u*5+i)*5+j];
    }
    #pragma unroll
    for(int o=0;o<5;++o){ float g=0.f;                       // p6
      #pragma unroll
      for(int i=0;i<5;++i) g += KL[155+o*5+i]*m2p[i];
      acc[o]=rw0*g; }
    { float g=0.f;                                           // p7
      #pragma unroll
      for(int i=0;i<5;++i)
        #pragma unroll
        for(int j=0;j<5;++j) g += KL[180+i*5+j]*m2s[i][j];
      acc[5]=rw1*g; }
    #pragma unroll
    for(int o=0;o<3;++o){ float g=0.f;                       // p8
      #pragma unroll
      for(int i=0;i<5;++i)
        #pragma unroll
        for(int j=0;j<5;++j) g += KL[205+(o*5+i)*5+j]*m2s[i][j];
      acc[6+o]=rw2*g; }
    #pragma unroll
    for(int o=0;o<5;++o){ float g=0.f;                       // p9
      #pragma unroll
      for(int i=0;i<5;++i)
        #pragma unroll
        for(int j=0;j<5;++j) g += KL[280+(o*5+i)*5+j]*m2s[i][j];
      acc[9+o]=rw3*g; }
  }

  // scatter into aS: concat m0=[p1,p7], m1=[p3,p4,p8], m2=[p2,p5,p6,p9]
  if (lane<32){
    aS[w][lane] = acc[0];
    #pragma unroll
    for(int o=0;o<5;++o) aS[w][160 + lane*5+o] = acc[1+o];
  } else if (lane<48){
    const int uu=lane-32;
    #pragma unroll
    for(int m=0;m<3;++m){ aS[w][40 + uu*3+m] = acc[m]; aS[w][40 + (16+uu)*3+m] = acc[3+m]; }
    #pragma unroll
    for(int o=0;o<5;++o) aS[w][160 + (32+uu)*5+o] = acc[6+o];
  } else if (lane<56){
    const int uu=lane-48;
    aS[w][32+uu] = acc[5];
    #pragma unroll
    for(int m=0;m<3;++m) aS[w][40 + (32+uu)*3+m] = acc[6+m];
    #pragma unroll
    for(int o=0;o<5;++o){ aS[w][160 + (48+uu)*5+o] = acc[o]; aS[w][160 + (56+uu)*5+o] = acc[9+o]; }
  }
  __syncthreads();

  // Stage 3: linear mixes, write yf[n][120]
  const float inv40 = 0.15811388300841896660f;
  for(int q=lane;q<120;q+=64){
    float out;
    if (q<32){
      float g=0.f;
      for(int uu=0;uu<40;++uu) g += aS[w][uu]*W0[uu*32+q];
      out = g*inv40;
    } else if (q<80){
      const int e=q-32, v=e/3, m=e%3;
      float g=0.f;
      for(int uu=0;uu<40;++uu) g += aS[w][40+uu*3+m]*W1[uu*16+v];
      out = g*inv40;
    } else {
      const int e=q-80, tt=e/5, m=e%5;
      float g=0.f;
      for(int uu=0;uu<64;++uu) g += aS[w][160+uu*5+m]*W2[uu*8+tt];
      out = g*0.125f;
    }
    yf[(size_t)n*120+q] = out;
  }
}

// =================== stats partials: 96 ch x 8 chunks, deterministic disjoint writes ===================
__global__ __launch_bounds__(256) void k_statp(const float* __restrict__ yf,
                                               float* __restrict__ pA, float* __restrict__ pB){
  const int ch = blockIdx.x % 96;
  const int chunk = blockIdx.x / 96;
  const int t = threadIdx.x;
  const int n0 = chunk*1024;
  __shared__ float r1[256], r2[256];
  float a1=0.f, a2=0.f;
  if (ch<32){
    for(int nn=t;nn<1024;nn+=256){ float v=yf[(size_t)(n0+nn)*120+ch]; a1+=v; a2+=v*v; }
  } else if (ch<48){
    const int v_=ch-32;
    for(int nn=t;nn<1024;nn+=256){
      #pragma unroll
      for(int m=0;m<3;++m){ float v=yf[(size_t)(n0+nn)*120+32+v_*3+m]; a2+=v*v; }
    }
  } else {
    const int t_=ch-48;
    for(int nn=t;nn<1024;nn+=256){
      #pragma unroll
      for(int m=0;m<5;++m){ float v=yf[(size_t)(n0+nn)*120+80+t_*5+m]; a2+=v*v; }
    }
  }
  r1[t]=a1; r2[t]=a2; __syncthreads();
  for(int s=128;s>0;s>>=1){ if(t<s){ r1[t]+=r1[t+s]; r2[t]+=r2[t+s]; } __syncthreads(); }
  if(t==0){ pA[ch*8+chunk]=r1[0]; pB[ch*8+chunk]=r2[0]; }
}

// =================== normalize + relu + residual (layers 0,1): per-block finalize + apply ===================
__global__ __launch_bounds__(256) void k_norm(const float* __restrict__ yf,
                       const float* __restrict__ pA, const float* __restrict__ pB,
                       const float* __restrict__ bw0,const float* __restrict__ bb0,
                       const float* __restrict__ bw1,const float* __restrict__ bw2,
                       float* __restrict__ xf){
  __shared__ float sc[96], sf[32];
  const int t = threadIdx.x;
  if (t<96){
    float sB=0.f;
    #pragma unroll
    for(int k=0;k<8;++k) sB += pB[t*8+k];
    float scale;
    if (t<32){
      float sA=0.f;
      #pragma unroll
      for(int k=0;k<8;++k) sA += pA[t*8+k];
      const float mean = sA*(1.f/8192.f);
      const float var  = sB*(1.f/8192.f) - mean*mean;
      const float inv  = 1.f/sqrtf(var+1e-5f);
      scale = bw0[t]*inv;
      sf[t] = bb0[t] - mean*scale;
    } else if (t<48){
      scale = bw1[t-32]/sqrtf(sB*(1.f/(8192.f*3.f))+1e-5f);
    } else {
      scale = bw2[t-48]/sqrtf(sB*(1.f/(8192.f*5.f))+1e-5f);
    }
    sc[t]=scale;
  }
  __syncthreads();
  const int idx = blockIdx.x*256 + t;
  if (idx >= NN*120) return;
  const int c = idx%120;
  const int chan = (c<32)? c : ((c<80)? 32+(c-32)/3 : 48+(c-80)/5);
  const float v = yf[idx]*sc[chan] + ((c<32)? sf[c] : 0.f);
  xf[idx] += fmaxf(v,0.f);
}

// =================== fused layer-3 norm (x0 only; l1/l2 dead) + final MLP ===================
__global__ __launch_bounds__(256) void k_normmlp(const float* __restrict__ yf,
                                             const float* __restrict__ xf,
                                             const float* __restrict__ pA, const float* __restrict__ pB,
                                             const float* __restrict__ bw0,const float* __restrict__ bb0,
                                             const float* __restrict__ Wf1,const float* __restrict__ Wf2,
                                             const float* __restrict__ bf2,const float* __restrict__ Wf3,
                                             const float* __restrict__ bf3, float* __restrict__ out){
  __shared__ float w1[1024], w2[512], w3[32], b2[16], b3[2], sc0[32], sf0[32];
  const int t=threadIdx.x;
  for(int q=t;q<1024;q+=256) w1[q]=Wf1[q];
  for(int q=t;q<512;q+=256)  w2[q]=Wf2[q];
  if(t<32) w3[t]=Wf3[t];
  if(t<16) b2[t]=bf2[t];
  if(t<2)  b3[t]=bf3[t];
  if(t<32){
    float sA=0.f, sB=0.f;
    #pragma unroll
    for(int k=0;k<8;++k){ sA += pA[t*8+k]; sB += pB[t*8+k]; }
    const float mean = sA*(1.f/8192.f);
    const float var  = sB*(1.f/8192.f) - mean*mean;
    const float inv  = 1.f/sqrtf(var+1e-5f);
    sc0[t] = bw0[t]*inv;
    sf0[t] = bb0[t] - mean*sc0[t];
  }
  __syncthreads();
  const int n = blockIdx.x*256+t;
  if(n>=NN) return;
  float xv[32];
  #pragma unroll
  for(int k=0;k<32;++k){
    const float v = yf[(size_t)n*120+k]*sc0[k] + sf0[k];
    xv[k] = xf[(size_t)n*120+k] + fmaxf(v,0.f);
  }
  const float inv32 = 0.17677669529663688110f;
  float h1[32];
  #pragma unroll 4
  for(int c=0;c<32;++c){ float g=0.f;
    #pragma unroll
    for(int k=0;k<32;++k) g+=xv[k]*w1[k*32+c];
    h1[c]=fmaxf(g*inv32,0.f); }
  float h2[16];
  #pragma unroll 4
  for(int c=0;c<16;++c){ float g=b2[c];
    #pragma unroll
    for(int k=0;k<32;++k) g+=h1[k]*w2[k*16+c];
    h2[c]=fmaxf(g,0.f); }
  #pragma unroll
  for(int m=0;m<2;++m){ float g=b3[m];
    #pragma unroll
    for(int k=0;k<16;++k) g+=h2[k]*w3[k*2+m];
    out[n*2+m]=g; }
}

extern "C" void kernel_launch(void* const* d_in, const int* in_sizes, int n_in,
                              void* d_out, int out_size, void* d_ws, size_t ws_size,
                              hipStream_t stream) {
  const float* positions = (const float*)d_in[0];
  const float* W_emb  = (const float*)d_in[1];
  const float* tp_w   = (const float*)d_in[2];
  const float* lin_W0 = (const float*)d_in[3];
  const float* lin_W1 = (const float*)d_in[4];
  const float* lin_W2 = (const float*)d_in[5];
  const float* bn_w0  = (const float*)d_in[6];
  const float* bn_b0  = (const float*)d_in[7];
  const float* bn_w1  = (const float*)d_in[8];
  const float* bn_w2  = (const float*)d_in[9];
  const float* Wf1 = (const float*)d_in[10];
  const float* Wf2 = (const float*)d_in[11];
  const float* bf2 = (const float*)d_in[12];
  const float* Wf3 = (const float*)d_in[13];
  const float* bf3 = (const float*)d_in[14];

  if (ws_size < WS_FLOATS*sizeof(float)) return;

  float* ws    = (float*)d_ws;
  float* Kbuf  = ws + OFF_K;
  int*   cnt   = (int*)(ws + OFF_CNT);
  int*   rev   = (int*)(ws + OFF_REV);
  float* stats = ws + OFF_STATS;   // 3 layers x (768 pA | 768 pB)
  float* xf = ws + OFF_XF;
  float* yf = ws + OFF_YF;

  // SoA position arrays alias the head of yf (dead after k_knn7; first k_msg rewrites yf)
  float* xs = yf;
  float* ysA = yf + NN;
  float* zs = yf + 2*NN;
  float* qs = yf + 3*NN;

  k_setup<<<3906,256,0,stream>>>(positions, W_emb, Kbuf, xf, xs, ysA, zs, qs, cnt);
  k_knn7<<<NN/4,256,0,stream>>>(xs, ysA, zs, qs, cnt, rev);

  for(int l=0;l<3;++l){
    float* pA = stats + l*1536;
    float* pB = pA + 768;
    k_msg<<<NN/4,256,0,stream>>>(positions, cnt, rev, Kbuf, xf,
                              tp_w + l*144, lin_W0 + l*40*32, lin_W1 + l*40*16, lin_W2 + l*64*8,
                              yf);
    k_statp<<<768,256,0,stream>>>(yf, pA, pB);
    if (l<2){
      k_norm<<<(NN*120+255)/256,256,0,stream>>>(yf, pA, pB,
                              bn_w0 + l*32, bn_b0 + l*32, bn_w1 + l*16, bn_w2 + l*8,
                              xf);
    }
  }
  k_normmlp<<<NN/256,256,0,stream>>>(yf, xf, stats + 2*1536, stats + 2*1536 + 768,
                              bn_w0 + 64, bn_b0 + 64,
                              Wf1, Wf2, bf2, Wf3, bf3, (float*)d_out);
}

// Round 15
// 298.575 us; speedup vs baseline: 3.8857x; 1.0383x over previous
//
#include <hip/hip_runtime.h>
#include <math.h>

#define NN 8192
#define REV_CAP 48
#define KNN_CAP 384   // per-wave survivor cap (E[survivors]~72; P(overflow) astronomically small)
#define PF 12         // k_msg edge-gather prefetch depth

// ---- ws layout (float element offsets) ----
static const size_t OFF_K     = 0;        // 405
static const size_t OFF_CNT   = 512;      // int[8192]
static const size_t OFF_REV   = 8704;     // int[8192*48]
static const size_t OFF_STATS = 401920;   // 3 layers x (768 A-partials + 768 B-partials)
static const size_t OFF_XF    = 406528;   // 8192*120 interleaved features
static const size_t OFF_YF    = 1389568;  // 8192*120 outputs (head aliased as SoA x/y/z/q for KNN)
static const size_t WS_FLOATS = 2372608;

// =================== K tensor math (device, double precision) ===================
__device__ double dfact(int n){ double r=1.0; for(int i=2;i<=n;++i) r*=(double)i; return r; }

__device__ double dcg(int j1,int m1,int j2,int m2,int j3,int m3){
  if (m1+m2!=m3) return 0.0;
  if (j3 < abs(j1-j2) || j3 > j1+j2) return 0.0;
  double pre = sqrt((double)(2*j3+1)*dfact(j3+j1-j2)*dfact(j3-j1+j2)*dfact(j1+j2-j3)/dfact(j1+j2+j3+1));
  pre *= sqrt(dfact(j3+m3)*dfact(j3-m3)*dfact(j1-m1)*dfact(j1+m1)*dfact(j2-m2)*dfact(j2+m2));
  double s=0.0;
  for(int k=0;k<=j1+j2-j3;++k){
    int d1=j1+j2-j3-k, d2=j1-m1-k, d3=j2+m2-k, d4=j3-j2+m1+k, d5=j3-j1-m2+k;
    if(d1<0||d2<0||d3<0||d4<0||d5<0) continue;
    double den = dfact(k)*dfact(d1)*dfact(d2)*dfact(d3)*dfact(d4)*dfact(d5);
    s += ((k&1)? -1.0: 1.0)/den;
  }
  return pre*s;
}

__device__ int qrow(int l,int r,int* col,double* re,double* im){
  const double s = 0.70710678118654752440;
  if (r==l){ col[0]=l; re[0]=1.0; im[0]=0.0; return 1; }
  if (r>l){ int m=r-l;
    col[0]=l+m; re[0]=((m&1)?-s:s); im[0]=0.0;
    col[1]=l-m; re[1]=s;            im[1]=0.0;
  } else { int m=l-r;
    col[0]=l+m; re[0]=0.0; im[0]=((m&1)? s : -s);
    col[1]=l-m; re[1]=0.0; im[1]=s;
  }
  return 2;
}

// =================== fused setup: xf init | SoA+q | cnt | K ===================
__global__ __launch_bounds__(256) void k_setup(const float* __restrict__ pos,
        const float* __restrict__ W_emb, float* __restrict__ Kbuf,
        float* __restrict__ xf,
        float* __restrict__ xs, float* __restrict__ ys, float* __restrict__ zs,
        float* __restrict__ qs,
        int* __restrict__ cnt){
  int idx = blockIdx.x*256 + threadIdx.x;
  if (idx < 983040) { const int c = idx%120; xf[idx] = (c<32)? W_emb[c] : 0.f; return; }
  idx -= 983040;
  if (idx < 8192) {
    const float x=pos[3*idx], y=pos[3*idx+1], z=pos[3*idx+2];
    xs[idx]=x; ys[idx]=y; zs[idx]=z; qs[idx]=0.5f*(x*x+y*y+z*z);
    return;
  }
  idx -= 8192;
  if (idx < 8192) { cnt[idx]=0; return; }
  idx -= 8192;
  if (idx >= 405) return;

  const int tid = idx;
  const int sizes[9]={1,25,9,45,75,25,25,75,125};
  const int l1s[9]={0,0,1,1,1,2,2,2,2};
  const int l2s[9]={0,2,0,2,2,0,2,2,2};
  const int l3s[9]={0,2,1,1,2,2,0,1,2};
  int p=0, rem=tid;
  for(p=0;p<9;++p){ if(rem < sizes[p]) break; rem -= sizes[p]; }
  const int l1=l1s[p], l2=l2s[p], l3=l3s[p];
  const int n1=2*l1+1, n2=2*l2+1;
  const int c = rem/(n1*n2); const int r2 = rem%(n1*n2); const int a=r2/n2; const int b=r2%n2;

  int c3[2],c1[2],c2[2]; double re3[2],im3[2],re1[2],im1[2],re2[2],im2[2];
  const int nc3 = qrow(l3,c,c3,re3,im3);
  const int nc1 = qrow(l1,a,c1,re1,im1);
  const int nc2 = qrow(l2,b,c2,re2,im2);

  double accRe=0, accIm=0;
  for(int i3=0;i3<nc3;++i3){
    const double q3re=re3[i3], q3im=-im3[i3];
    for(int i1=0;i1<nc1;++i1){
      const double pre_re = q3re*re1[i1] - q3im*im1[i1];
      const double pre_im = q3re*im1[i1] + q3im*re1[i1];
      for(int i2=0;i2<nc2;++i2){
        const double cgv = dcg(l1, c1[i1]-l1, l2, c2[i2]-l2, l3, c3[i3]-l3);
        if (cgv==0.0) continue;
        accRe += (pre_re*re2[i2] - pre_im*im2[i2])*cgv;
        accIm += (pre_re*im2[i2] + pre_im*re2[i2])*cgv;
      }
    }
  }
  const bool useImag = ((l1+l2+l3)&1)!=0;
  Kbuf[tid] = (float)(useImag? accIm : accRe);
}

// =================== exact 9-NN: knn4 verbatim (1024-sample bound), CAP 384 ===================
__global__ __launch_bounds__(256) void k_knn8(const float* __restrict__ xs,
                                              const float* __restrict__ ys,
                                              const float* __restrict__ zs,
                                              const float* __restrict__ qs,
                                              int* __restrict__ cnt, int* __restrict__ rev){
  const int lane = threadIdx.x & 63;
  const int w    = threadIdx.x >> 6;
  const int node = blockIdx.x*4 + w;
  __shared__ float sdist[4][KNN_CAP];
  __shared__ int   sidx[4][KNN_CAP];
  __shared__ int   scount[4];
  if (threadIdx.x < 4) scount[threadIdx.x]=0;
  __syncthreads();

  const float px = xs[node], py = ys[node], pz = zs[node];

  // Phase 1: per-lane top-2 over first 1024 candidates, branchless -> bound T
  float m1 = INFINITY, m2 = INFINITY;
  for(int c=0;c<4;++c){
    const int base = (c*64 + lane)*4;
    const float4 fx = *(const float4*)(xs + base);
    const float4 fy = *(const float4*)(ys + base);
    const float4 fz = *(const float4*)(zs + base);
    const float4 fq = *(const float4*)(qs + base);
    float ss[4];
    ss[0] = fmaf(-px,fx.x, fmaf(-py,fy.x, fmaf(-pz,fz.x, fq.x)));
    ss[1] = fmaf(-px,fx.y, fmaf(-py,fy.y, fmaf(-pz,fz.y, fq.y)));
    ss[2] = fmaf(-px,fx.z, fmaf(-py,fy.z, fmaf(-pz,fz.z, fq.z)));
    ss[3] = fmaf(-px,fx.w, fmaf(-py,fy.w, fmaf(-pz,fz.w, fq.w)));
    #pragma unroll
    for(int q=0;q<4;++q){
      const float hi = fmaxf(m1, ss[q]);
      m1 = fminf(m1, ss[q]);
      m2 = fminf(m2, hi);
    }
  }
  float T = INFINITY;
  for(int r=0;r<9;++r){
    float v = m1; int l = lane;
    #pragma unroll
    for(int s=32;s>0;s>>=1){
      const float ov=__shfl_xor(v,s,64); const int ol=__shfl_xor(l,s,64);
      if (ov<v || (ov==v && ol<l)){ v=ov; l=ol; }
    }
    T = v;
    if (lane==l){ m1=m2; m2=INFINITY; }
  }

  // Phase 2: filter all 8192 candidates by s <= T
  for(int c=0;c<32;++c){
    const int base = (c*64 + lane)*4;
    const float4 fx = *(const float4*)(xs + base);
    const float4 fy = *(const float4*)(ys + base);
    const float4 fz = *(const float4*)(zs + base);
    const float4 fq = *(const float4*)(qs + base);
    float ss[4];
    ss[0] = fmaf(-px,fx.x, fmaf(-py,fy.x, fmaf(-pz,fz.x, fq.x)));
    ss[1] = fmaf(-px,fx.y, fmaf(-py,fy.y, fmaf(-pz,fz.y, fq.y)));
    ss[2] = fmaf(-px,fx.z, fmaf(-py,fy.z, fmaf(-pz,fz.z, fq.z)));
    ss[3] = fmaf(-px,fx.w, fmaf(-py,fy.w, fmaf(-pz,fz.w, fq.w)));
    #pragma unroll
    for(int q=0;q<4;++q){
      if (ss[q] <= T){
        int pos = atomicAdd(&scount[w],1);
        if (pos < KNN_CAP){ sdist[w][pos]=ss[q]; sidx[w][pos]=base+q; }
      }
    }
  }
  __syncthreads();

  // Phase 3: exact top-9 over survivors, (s,id)-lexicographic
  int m = scount[w]; if (m > KNN_CAP) m = KNN_CAP;
  float dl[KNN_CAP/64]; int il[KNN_CAP/64];
  #pragma unroll
  for(int k=0;k<KNN_CAP/64;++k){
    const int j = lane + 64*k;
    if (j < m){ dl[k]=sdist[w][j]; il[k]=sidx[w][j]; }
    else      { dl[k]=INFINITY;    il[k]=0x7fffffff; }
  }
  for(int r=0;r<9;++r){
    float bv=dl[0]; int bi=il[0];
    #pragma unroll
    for(int k=1;k<KNN_CAP/64;++k){
      if (dl[k]<bv || (dl[k]==bv && il[k]<bi)){ bv=dl[k]; bi=il[k]; }
    }
    float v=bv; int ix=bi;
    #pragma unroll
    for(int s=32;s>0;s>>=1){
      float ov=__shfl_xor(v,s,64); int oi=__shfl_xor(ix,s,64);
      if (ov<v || (ov==v && oi<ix)){ v=ov; ix=oi; }
    }
    if (ix != node && lane==0){
      int cpos = atomicAdd(&cnt[ix],1);
      if (cpos < REV_CAP) rev[ix*REV_CAP + cpos] = node;
    }
    #pragma unroll
    for(int k=0;k<KNN_CAP/64;++k){
      if (il[k]==ix){ dl[k]=INFINITY; il[k]=0x7fffffff; }
    }
  }
}

// =================== moment-based message passing: prefetched edge gathers (r14 verbatim) ===================
__global__ __launch_bounds__(256) void k_msg(
  const float* __restrict__ pos,
  const int* __restrict__ cnt, const int* __restrict__ rev,
  const float* __restrict__ Kbuf,
  const float* __restrict__ xf,
  const float* __restrict__ tpw,
  const float* __restrict__ W0, const float* __restrict__ W1, const float* __restrict__ W2,
  float* __restrict__ yf)
{
  const int t = threadIdx.x;
  const int w = t >> 6;
  const int lane = t & 63;
  const int n = blockIdx.x*4 + w;

  __shared__ float KL[405];
  __shared__ float TW[144];
  __shared__ float momP[4][120];
  __shared__ float momS[4][600];
  __shared__ float aS[4][480];
  __shared__ int   eIdx[4][REV_CAP];
  __shared__ float eSh[4][5][REV_CAP];
  for(int q=t;q<405;q+=256) KL[q]=Kbuf[q];
  for(int q=t;q<144;q+=256) TW[q]=tpw[q];

  // Stage 1a: parallel edge geometry (lane e < deg owns edge e)
  const int deg0 = cnt[n];
  const int deg = (deg0<REV_CAP)? deg0 : REV_CAP;
  const float pnx=pos[3*n], pny=pos[3*n+1], pnz=pos[3*n+2];
  const float s15 = 3.8729833462f, s5c = 2.2360679775f;
  if (lane < deg){
    const int i = rev[n*REV_CAP+lane];
    eIdx[w][lane] = i;
    const float ex = pnx - pos[3*i], ey = pny - pos[3*i+1], ez = pnz - pos[3*i+2];
    const float rn = sqrtf(ex*ex+ey*ey+ez*ez) + 1e-12f;
    const float ux=ex/rn, uy=ey/rn, uz=ez/rn;
    eSh[w][0][lane]=s15*ux*uy;
    eSh[w][1][lane]=s15*uy*uz;
    eSh[w][2][lane]=0.5f*s5c*(3.f*uz*uz-1.f);
    eSh[w][3][lane]=s15*ux*uz;
    eSh[w][4][lane]=0.5f*s15*(ux*ux-uy*uy);
  }
  __syncthreads();

  // Stage 1b: moment accumulation with prefetched gathers
  const int c0 = lane*2;
  float mp0=0.f, mp1=0.f;
  float ms0[5], ms1[5];
  #pragma unroll
  for(int j=0;j<5;++j){ ms0[j]=0.f; ms1[j]=0.f; }

  int idxr[PF];
  #pragma unroll
  for(int k=0;k<PF;++k) idxr[k] = (k<deg)? eIdx[w][k] : 0;
  float2 fr[PF];
  if (lane<60){
    #pragma unroll
    for(int k=0;k<PF;++k) fr[k] = *(const float2*)(xf + (size_t)idxr[k]*120 + c0);
  }
  #pragma unroll
  for(int k=0;k<PF;++k){
    if (k<deg){
      const float sh0=eSh[w][0][k], sh1=eSh[w][1][k], sh2=eSh[w][2][k];
      const float sh3=eSh[w][3][k], sh4=eSh[w][4][k];
      if (lane<60){
        const float2 f = fr[k];
        mp0 += f.x; mp1 += f.y;
        ms0[0]+=f.x*sh0; ms0[1]+=f.x*sh1; ms0[2]+=f.x*sh2; ms0[3]+=f.x*sh3; ms0[4]+=f.x*sh4;
        ms1[0]+=f.y*sh0; ms1[1]+=f.y*sh1; ms1[2]+=f.y*sh2; ms1[3]+=f.y*sh3; ms1[4]+=f.y*sh4;
      }
    }
  }
  for(int e=PF;e<deg;++e){   // rare tail (deg>PF)
    const int i = eIdx[w][e];
    const float sh0=eSh[w][0][e], sh1=eSh[w][1][e], sh2=eSh[w][2][e];
    const float sh3=eSh[w][3][e], sh4=eSh[w][4][e];
    if (lane<60){
      const float2 f = *(const float2*)(xf + (size_t)i*120 + c0);
      mp0 += f.x; mp1 += f.y;
      ms0[0]+=f.x*sh0; ms0[1]+=f.x*sh1; ms0[2]+=f.x*sh2; ms0[3]+=f.x*sh3; ms0[4]+=f.x*sh4;
      ms1[0]+=f.y*sh0; ms1[1]+=f.y*sh1; ms1[2]+=f.y*sh2; ms1[3]+=f.y*sh3; ms1[4]+=f.y*sh4;
    }
  }
  if (lane<60){
    momP[w][c0]=mp0; momP[w][c0+1]=mp1;
    #pragma unroll
    for(int j=0;j<5;++j){ momS[w][c0*5+j]=ms0[j]; momS[w][(c0+1)*5+j]=ms1[j]; }
  }
  __syncthreads();

  // Stage 2: per-node K-contraction on moments
  float acc[14];
  #pragma unroll
  for(int k=0;k<14;++k) acc[k]=0.f;

  if (lane<32){
    const int u=lane;
    const float rw0=TW[u], rw1=TW[32+u];
    acc[0] = rw0 * KL[0] * momP[w][u];                       // p1
    float m0s[5];
    #pragma unroll
    for(int j=0;j<5;++j) m0s[j]=momS[w][u*5+j];
    #pragma unroll
    for(int o=0;o<5;++o){ float g=0.f;                       // p2
      #pragma unroll
      for(int j=0;j<5;++j) g += KL[1+o*5+j]*m0s[j];
      acc[1+o] = rw1*g; }
  } else if (lane<48){
    const int u=lane-32;
    const float rw0=TW[64+u], rw1=TW[80+u], rw2=TW[96+u];
    float m1p[3], m1s[3][5];
    #pragma unroll
    for(int i=0;i<3;++i){
      m1p[i]=momP[w][32+u*3+i];
      #pragma unroll
      for(int j=0;j<5;++j) m1s[i][j]=momS[w][(32+u*3+i)*5+j];
    }
    #pragma unroll
    for(int o=0;o<3;++o){ float g=0.f;                       // p3
      #pragma unroll
      for(int i=0;i<3;++i) g += KL[26+o*3+i]*m1p[i];
      acc[o]=rw0*g; }
    #pragma unroll
    for(int o=0;o<3;++o){ float g=0.f;                       // p4
      #pragma unroll
      for(int i=0;i<3;++i)
        #pragma unroll
        for(int j=0;j<5;++j) g += KL[35+(o*3+i)*5+j]*m1s[i][j];
      acc[3+o]=rw1*g; }
    #pragma unroll
    for(int o=0;o<5;++o){ float g=0.f;                       // p5
      #pragma unroll
      for(int i=0;i<3;++i)
        #pragma unroll
        for(int j=0;j<5;++j) g += KL[80+(o*3+i)*5+j]*m1s[i][j];
      acc[6+o]=rw2*g; }
  } else if (lane<56){
    const int u=lane-48;
    const float rw0=TW[112+u], rw1=TW[120+u], rw2=TW[128+u], rw3=TW[136+u];
    float m2p[5], m2s[5][5];
    #pragma unroll
    for(int i=0;i<5;++i){
      m2p[i]=momP[w][80+u*5+i];
      #pragma unroll
      for(int j=0;j<5;++j) m2s[i][j]=momS[w][(80+u*5+i)*5+j];
    }
    #pragma unroll
    for(int o=0;o<5;++o){ float g=0.f;                       // p6
      #pragma unroll
      for(int i=0;i<5;++i) g += KL[155+o*5+i]*m2p[i];
      acc[o]=rw0*g; }
    { float g=0.f;                                           // p7
      #pragma unroll
      for(int i=0;i<5;++i)
        #pragma unroll
        for(int j=0;j<5;++j) g += KL[180+i*5+j]*m2s[i][j];
      acc[5]=rw1*g; }
    #pragma unroll
    for(int o=0;o<3;++o){ float g=0.f;                       // p8
      #pragma unroll
      for(int i=0;i<5;++i)
        #pragma unroll
        for(int j=0;j<5;++j) g += KL[205+(o*5+i)*5+j]*m2s[i][j];
      acc[6+o]=rw2*g; }
    #pragma unroll
    for(int o=0;o<5;++o){ float g=0.f;                       // p9
      #pragma unroll
      for(int i=0;i<5;++i)
        #pragma unroll
        for(int j=0;j<5;++j) g += KL[280+(o*5+i)*5+j]*m2s[i][j];
      acc[9+o]=rw3*g; }
  }

  // scatter into aS: concat m0=[p1,p7], m1=[p3,p4,p8], m2=[p2,p5,p6,p9]
  if (lane<32){
    aS[w][lane] = acc[0];
    #pragma unroll
    for(int o=0;o<5;++o) aS[w][160 + lane*5+o] = acc[1+o];
  } else if (lane<48){
    const int uu=lane-32;
    #pragma unroll
    for(int m=0;m<3;++m){ aS[w][40 + uu*3+m] = acc[m]; aS[w][40 + (16+uu)*3+m] = acc[3+m]; }
    #pragma unroll
    for(int o=0;o<5;++o) aS[w][160 + (32+uu)*5+o] = acc[6+o];
  } else if (lane<56){
    const int uu=lane-48;
    aS[w][32+uu] = acc[5];
    #pragma unroll
    for(int m=0;m<3;++m) aS[w][40 + (32+uu)*3+m] = acc[6+m];
    #pragma unroll
    for(int o=0;o<5;++o){ aS[w][160 + (48+uu)*5+o] = acc[o]; aS[w][160 + (56+uu)*5+o] = acc[9+o]; }
  }
  __syncthreads();

  // Stage 3: linear mixes, write yf[n][120]
  const float inv40 = 0.15811388300841896660f;
  for(int q=lane;q<120;q+=64){
    float out;
    if (q<32){
      float g=0.f;
      for(int uu=0;uu<40;++uu) g += aS[w][uu]*W0[uu*32+q];
      out = g*inv40;
    } else if (q<80){
      const int e=q-32, v=e/3, m=e%3;
      float g=0.f;
      for(int uu=0;uu<40;++uu) g += aS[w][40+uu*3+m]*W1[uu*16+v];
      out = g*inv40;
    } else {
      const int e=q-80, tt=e/5, m=e%5;
      float g=0.f;
      for(int uu=0;uu<64;++uu) g += aS[w][160+uu*5+m]*W2[uu*8+tt];
      out = g*0.125f;
    }
    yf[(size_t)n*120+q] = out;
  }
}

// =================== stats partials: 96 ch x 8 chunks, deterministic disjoint writes ===================
__global__ __launch_bounds__(256) void k_statp(const float* __restrict__ yf,
                                               float* __restrict__ pA, float* __restrict__ pB){
  const int ch = blockIdx.x % 96;
  const int chunk = blockIdx.x / 96;
  const int t = threadIdx.x;
  const int n0 = chunk*1024;
  __shared__ float r1[256], r2[256];
  float a1=0.f, a2=0.f;
  if (ch<32){
    for(int nn=t;nn<1024;nn+=256){ float v=yf[(size_t)(n0+nn)*120+ch]; a1+=v; a2+=v*v; }
  } else if (ch<48){
    const int v_=ch-32;
    for(int nn=t;nn<1024;nn+=256){
      #pragma unroll
      for(int m=0;m<3;++m){ float v=yf[(size_t)(n0+nn)*120+32+v_*3+m]; a2+=v*v; }
    }
  } else {
    const int t_=ch-48;
    for(int nn=t;nn<1024;nn+=256){
      #pragma unroll
      for(int m=0;m<5;++m){ float v=yf[(size_t)(n0+nn)*120+80+t_*5+m]; a2+=v*v; }
    }
  }
  r1[t]=a1; r2[t]=a2; __syncthreads();
  for(int s=128;s>0;s>>=1){ if(t<s){ r1[t]+=r1[t+s]; r2[t]+=r2[t+s]; } __syncthreads(); }
  if(t==0){ pA[ch*8+chunk]=r1[0]; pB[ch*8+chunk]=r2[0]; }
}

// =================== normalize + relu + residual (layers 0,1): per-block finalize + apply ===================
__global__ __launch_bounds__(256) void k_norm(const float* __restrict__ yf,
                       const float* __restrict__ pA, const float* __restrict__ pB,
                       const float* __restrict__ bw0,const float* __restrict__ bb0,
                       const float* __restrict__ bw1,const float* __restrict__ bw2,
                       float* __restrict__ xf){
  __shared__ float sc[96], sf[32];
  const int t = threadIdx.x;
  if (t<96){
    float sB=0.f;
    #pragma unroll
    for(int k=0;k<8;++k) sB += pB[t*8+k];
    float scale;
    if (t<32){
      float sA=0.f;
      #pragma unroll
      for(int k=0;k<8;++k) sA += pA[t*8+k];
      const float mean = sA*(1.f/8192.f);
      const float var  = sB*(1.f/8192.f) - mean*mean;
      const float inv  = 1.f/sqrtf(var+1e-5f);
      scale = bw0[t]*inv;
      sf[t] = bb0[t] - mean*scale;
    } else if (t<48){
      scale = bw1[t-32]/sqrtf(sB*(1.f/(8192.f*3.f))+1e-5f);
    } else {
      scale = bw2[t-48]/sqrtf(sB*(1.f/(8192.f*5.f))+1e-5f);
    }
    sc[t]=scale;
  }
  __syncthreads();
  const int idx = blockIdx.x*256 + t;
  if (idx >= NN*120) return;
  const int c = idx%120;
  const int chan = (c<32)? c : ((c<80)? 32+(c-32)/3 : 48+(c-80)/5);
  const float v = yf[idx]*sc[chan] + ((c<32)? sf[c] : 0.f);
  xf[idx] += fmaxf(v,0.f);
}

// =================== fused layer-3 norm (x0 only; l1/l2 dead) + final MLP ===================
__global__ __launch_bounds__(256) void k_normmlp(const float* __restrict__ yf,
                                             const float* __restrict__ xf,
                                             const float* __restrict__ pA, const float* __restrict__ pB,
                                             const float* __restrict__ bw0,const float* __restrict__ bb0,
                                             const float* __restrict__ Wf1,const float* __restrict__ Wf2,
                                             const float* __restrict__ bf2,const float* __restrict__ Wf3,
                                             const float* __restrict__ bf3, float* __restrict__ out){
  __shared__ float w1[1024], w2[512], w3[32], b2[16], b3[2], sc0[32], sf0[32];
  const int t=threadIdx.x;
  for(int q=t;q<1024;q+=256) w1[q]=Wf1[q];
  for(int q=t;q<512;q+=256)  w2[q]=Wf2[q];
  if(t<32) w3[t]=Wf3[t];
  if(t<16) b2[t]=bf2[t];
  if(t<2)  b3[t]=bf3[t];
  if(t<32){
    float sA=0.f, sB=0.f;
    #pragma unroll
    for(int k=0;k<8;++k){ sA += pA[t*8+k]; sB += pB[t*8+k]; }
    const float mean = sA*(1.f/8192.f);
    const float var  = sB*(1.f/8192.f) - mean*mean;
    const float inv  = 1.f/sqrtf(var+1e-5f);
    sc0[t] = bw0[t]*inv;
    sf0[t] = bb0[t] - mean*sc0[t];
  }
  __syncthreads();
  const int n = blockIdx.x*256+t;
  if(n>=NN) return;
  float xv[32];
  #pragma unroll
  for(int k=0;k<32;++k){
    const float v = yf[(size_t)n*120+k]*sc0[k] + sf0[k];
    xv[k] = xf[(size_t)n*120+k] + fmaxf(v,0.f);
  }
  const float inv32 = 0.17677669529663688110f;
  float h1[32];
  #pragma unroll 4
  for(int c=0;c<32;++c){ float g=0.f;
    #pragma unroll
    for(int k=0;k<32;++k) g+=xv[k]*w1[k*32+c];
    h1[c]=fmaxf(g*inv32,0.f); }
  float h2[16];
  #pragma unroll 4
  for(int c=0;c<16;++c){ float g=b2[c];
    #pragma unroll
    for(int k=0;k<32;++k) g+=h1[k]*w2[k*16+c];
    h2[c]=fmaxf(g,0.f); }
  #pragma unroll
  for(int m=0;m<2;++m){ float g=b3[m];
    #pragma unroll
    for(int k=0;k<16;++k) g+=h2[k]*w3[k*2+m];
    out[n*2+m]=g; }
}

extern "C" void kernel_launch(void* const* d_in, const int* in_sizes, int n_in,
                              void* d_out, int out_size, void* d_ws, size_t ws_size,
                              hipStream_t stream) {
  const float* positions = (const float*)d_in[0];
  const float* W_emb  = (const float*)d_in[1];
  const float* tp_w   = (const float*)d_in[2];
  const float* lin_W0 = (const float*)d_in[3];
  const float* lin_W1 = (const float*)d_in[4];
  const float* lin_W2 = (const float*)d_in[5];
  const float* bn_w0  = (const float*)d_in[6];
  const float* bn_b0  = (const float*)d_in[7];
  const float* bn_w1  = (const float*)d_in[8];
  const float* bn_w2  = (const float*)d_in[9];
  const float* Wf1 = (const float*)d_in[10];
  const float* Wf2 = (const float*)d_in[11];
  const float* bf2 = (const float*)d_in[12];
  const float* Wf3 = (const float*)d_in[13];
  const float* bf3 = (const float*)d_in[14];

  if (ws_size < WS_FLOATS*sizeof(float)) return;

  float* ws    = (float*)d_ws;
  float* Kbuf  = ws + OFF_K;
  int*   cnt   = (int*)(ws + OFF_CNT);
  int*   rev   = (int*)(ws + OFF_REV);
  float* stats = ws + OFF_STATS;   // 3 layers x (768 pA | 768 pB)
  float* xf = ws + OFF_XF;
  float* yf = ws + OFF_YF;

  // SoA position arrays alias the head of yf (dead after k_knn8; first k_msg rewrites yf)
  float* xs = yf;
  float* ysA = yf + NN;
  float* zs = yf + 2*NN;
  float* qs = yf + 3*NN;

  k_setup<<<3906,256,0,stream>>>(positions, W_emb, Kbuf, xf, xs, ysA, zs, qs, cnt);
  k_knn8<<<NN/4,256,0,stream>>>(xs, ysA, zs, qs, cnt, rev);

  for(int l=0;l<3;++l){
    float* pA = stats + l*1536;
    float* pB = pA + 768;
    k_msg<<<NN/4,256,0,stream>>>(positions, cnt, rev, Kbuf, xf,
                              tp_w + l*144, lin_W0 + l*40*32, lin_W1 + l*40*16, lin_W2 + l*64*8,
                              yf);
    k_statp<<<768,256,0,stream>>>(yf, pA, pB);
    if (l<2){
      k_norm<<<(NN*120+255)/256,256,0,stream>>>(yf, pA, pB,
                              bn_w0 + l*32, bn_b0 + l*32, bn_w1 + l*16, bn_w2 + l*8,
                              xf);
    }
  }
  k_normmlp<<<NN/256,256,0,stream>>>(yf, xf, stats + 2*1536, stats + 2*1536 + 768,
                              bn_w0 + 64, bn_b0 + 64,
                              Wf1, Wf2, bf2, Wf3, bf3, (float*)d_out);
}